// Round 1
// baseline (624.004 us; speedup 1.0000x reference)
//

#include <hip/hip_runtime.h>
#include <hip/hip_bf16.h>

// Deterministic hard_voxelize. Round 16: replace the global hash-table insert
// (2M random atomicCAS into 33.5MB table -> 176MB scattered 64B writebacks
// @1.45TB/s = 124us) with bucketed LDS direct-map dedup:
//   bin1  : points -> keys/flags + sharded bucket histogram (coalesced)
//   scanB : exact sub-segment offsets (1 block)
//   bin2  : scatter (key,idx) pairs into exact segments (~16MB, L2-held tails)
//   dedup : 1 workgroup/bucket, 8192-entry u32 LDS table (key space 90.48M /
//           2^13 = 11045 buckets, direct-mapped, no collisions), atomicMin by
//           point idx == first-occurrence semantics; emits resolved extras
//           (f,pidx) and clears dup flags (fuses old k_clear).
// k_init no longer memsets a table; k_assign reads keys[] (no pts, no tab).
// Measured laws: scattered 64B-line RMW ~1.45TB/s; single-hot-line device
// atomics ~7ns (R12) -> 8-way shard keeps hist/fill lines under service rate.

#define MAXV 150000
#define MAXP 10
#define LCAP 12
#define GXC 1504
#define GYC 1504
#define GZC 40

#define BSHIFT 13
#define BSIZE (1 << BSHIFT)      // 8192 keys per bucket, 32KB LDS table
#define NBUCK 11045              // 1504*1504*40 / 8192 exactly
#define NSHARD 8
#define MSUB (NBUCK * NSHARD)    // 88360 sub-segments
#define SEGC 16                  // extras segment per bucket (avg ~7 dups)
#define OCAP (1 << 15)           // global overflow (adversarial only)

#define OUT_COORS 7500000
#define OUT_NPV   7950000
#define OUT_VNUM  8100000

typedef unsigned char u8;
typedef unsigned short u16;
typedef unsigned int u32;
typedef unsigned long long u64;

__device__ __forceinline__ u16 f2bf(float v) {  // round-to-nearest-even
    u32 b = __float_as_uint(v);
    return (u16)((b + 0x7FFFu + ((b >> 16) & 1u)) >> 16);
}
__device__ __forceinline__ float bf2f(u16 u) {
    return __uint_as_float(((u32)u) << 16);
}
__device__ __forceinline__ float bfround(float v) { return bf2f(f2bf(v)); }

// Init (+ fused dtype detect in block 0): hist=0, cnt=0, counters=0.
__global__ void k_init(u32* hist, int* cnt, int N, const u16* raw,
                       int* dflag, u32* ocount, int* total) {
    if (blockIdx.x == 0) {
        __shared__ int v32;
        __shared__ int v16;
        if (threadIdx.x == 0) { v32 = 0; v16 = 0; }
        __syncthreads();
        int r = (int)threadIdx.x * 37;
        if (r >= N) r = N > 0 ? N - 1 : 0;
        const float* p32 = (const float*)raw;
        float a3 = p32[r * 5 + 3];
        float a4 = p32[r * 5 + 4];
        float b3 = bf2f(raw[r * 5 + 3]);
        float b4 = bf2f(raw[r * 5 + 4]);
        int ok32 = (a3 == a3) && (a4 == a4) &&
                   (a3 >= -0.001f) && (a3 <= 1.001f) && (a4 >= -0.001f) && (a4 <= 1.001f);
        int okbf = (b3 == b3) && (b4 == b4) &&
                   (b3 >= -0.001f) && (b3 <= 1.001f) && (b4 >= -0.001f) && (b4 <= 1.001f);
        if (ok32) atomicAdd(&v32, 1);
        if (okbf) atomicAdd(&v16, 1);
        __syncthreads();
        if (threadIdx.x == 0) *dflag = (v16 > v32) ? 1 : 0;
    }
    int stride = gridDim.x * blockDim.x;
    int i0 = blockIdx.x * blockDim.x + threadIdx.x;
    for (int i = i0; i < MSUB; i += stride) hist[i] = 0u;
    for (int i = i0; i < MAXV; i += stride) cnt[i] = 0;
    if (i0 == 0) { *ocount = 0u; *total = 0; }
}

__device__ __forceinline__ float load_ch(const void* pts, int i, int j, int bf) {
    if (bf) return bf2f(((const u16*)pts)[i * 5 + j]);
    return ((const float*)pts)[i * 5 + j];
}

// Exact f32 sub+div+floor, matching reference arithmetic. -1 if out of range.
__device__ __forceinline__ int point_key(const void* pts, int i, int bf) {
    float x = load_ch(pts, i, 0, bf);
    float y = load_ch(pts, i, 1, bf);
    float z = load_ch(pts, i, 2, bf);
    int cx = (int)floorf((x - (-75.2f)) / 0.1f);
    int cy = (int)floorf((y - (-75.2f)) / 0.1f);
    int cz = (int)floorf((z - (-2.0f)) / 0.15f);
    if (cx < 0 || cx >= GXC || cy < 0 || cy >= GYC || cz < 0 || cz >= GZC) return -1;
    return (cz * GYC + cy) * GXC + cx;
}

// Canonical (heaviest) kernel: one coalesced points pass -> keys, flags,
// sharded bucket histogram. Shard by blockIdx&7 (matches bin2's formula so
// per-sub-segment counts are exact).
__global__ void Voxelization_87136296501765_kernel(
        const void* pts, int N, const int* dflag,
        int* keys, u8* flags, u32* hist) {
    int i = blockIdx.x * 256 + threadIdx.x;
    if (i >= N) return;
    int key = point_key(pts, i, *dflag);
    keys[i] = key;
    flags[i] = (u8)(key >= 0);
    if (key >= 0)
        atomicAdd(&hist[((u32)key >> BSHIFT) * NSHARD + (blockIdx.x & (NSHARD - 1))], 1u);
}

// Exclusive scan of 88360 sub-segment counts -> bstart (kept) + fill (mutable).
__global__ void k_scanB(const u32* hist, u32* bstart, u32* fill) {
    __shared__ u32 sh[1024];
    int t = threadIdx.x;
    const int C = (MSUB + 1023) / 1024;  // 87
    int lo = t * C;
    int hi = lo + C;
    if (hi > MSUB) hi = MSUB;
    u32 s = 0;
    for (int i = lo; i < hi; i++) s += hist[i];
    sh[t] = s;
    __syncthreads();
    for (int off = 1; off < 1024; off <<= 1) {
        u32 xv = (t >= off) ? sh[t - off] : 0u;
        __syncthreads();
        sh[t] += xv;
        __syncthreads();
    }
    u32 run = sh[t] - s;
    for (int i = lo; i < hi; i++) {
        bstart[i] = run;
        fill[i] = run;
        run += hist[i];
    }
}

// Scatter (key, idx) pairs into exact per-(bucket,shard) segments.
__global__ void k_bin2(const int* keys, int N, u32* fill, u64* pairs) {
    int i = blockIdx.x * 256 + threadIdx.x;
    if (i >= N) return;
    int key = keys[i];
    if (key < 0) return;
    int j = (int)(((u32)key >> BSHIFT) * NSHARD) + (blockIdx.x & (NSHARD - 1));
    u32 pos = atomicAdd(&fill[j], 1u);
    pairs[pos] = ((u64)(u32)key << 32) | (u32)i;
}

// Per-bucket LDS direct-map dedup. table[key&8191] = min point idx (= first
// occurrence, reference's stable order). Second pass: dup iff idx != min ->
// clear flag, emit resolved extra (f=min, pidx).
__global__ void __launch_bounds__(256) k_dedup(
        const u64* pairs, const u32* bstart, const u32* hist,
        u8* flags, u64* extras, u32* ebcount, u64* ovf, u32* ocount) {
    __shared__ u32 tabs[BSIZE];
    __shared__ u32 s_cnt;
    int b = blockIdx.x;
    int base = b * NSHARD;
    u32 st[NSHARD], cc[NSHARD];
    u32 tot = 0;
#pragma unroll
    for (int s = 0; s < NSHARD; s++) {
        st[s] = bstart[base + s];
        cc[s] = hist[base + s];
        tot += cc[s];
    }
    if (tot == 0) {
        if (threadIdx.x == 0) ebcount[b] = 0u;
        return;
    }
    uint4* t4 = (uint4*)tabs;
    for (int j = threadIdx.x; j < BSIZE / 4; j += 256)
        t4[j] = make_uint4(0xFFFFFFFFu, 0xFFFFFFFFu, 0xFFFFFFFFu, 0xFFFFFFFFu);
    if (threadIdx.x == 0) s_cnt = 0u;
    __syncthreads();
#pragma unroll
    for (int s = 0; s < NSHARD; s++) {
        u32 c = cc[s], stt = st[s];
        for (u32 j = threadIdx.x; j < c; j += 256) {
            u64 pr = pairs[stt + j];
            atomicMin(&tabs[(u32)(pr >> 32) & (BSIZE - 1)], (u32)pr);
        }
    }
    __syncthreads();
#pragma unroll
    for (int s = 0; s < NSHARD; s++) {
        u32 c = cc[s], stt = st[s];
        for (u32 j = threadIdx.x; j < c; j += 256) {
            u64 pr = pairs[stt + j];
            u32 i = (u32)pr;
            u32 f = tabs[(u32)(pr >> 32) & (BSIZE - 1)];
            if (f != i) {
                flags[i] = 0;
                u64 rec = ((u64)f << 32) | i;
                u32 pos = atomicAdd(&s_cnt, 1u);
                if (pos < SEGC) {
                    extras[(size_t)b * SEGC + pos] = rec;
                } else {
                    u32 op = atomicAdd(ocount, 1u);  // adversarial only
                    if (op < OCAP) ovf[op] = rec;
                }
            }
        }
    }
    __syncthreads();
    if (threadIdx.x == 0) ebcount[b] = s_cnt;
}

// flags -> prefix (separate array; flags preserved for k_assign) + bsums.
__global__ void k_scan1(const u8* flags, u8* prefix, int* bsums, int n) {
    __shared__ int sh[256];
    int t = threadIdx.x;
    int i = blockIdx.x * 256 + t;
    int v = (i < n) ? (int)flags[i] : 0;
    sh[t] = v;
    __syncthreads();
    for (int off = 1; off < 256; off <<= 1) {
        int xv = (t >= off) ? sh[t - off] : 0;
        __syncthreads();
        sh[t] += xv;
        __syncthreads();
    }
    if (i < n) prefix[i] = (u8)(sh[t] - v);
    if (t == 255) bsums[blockIdx.x] = sh[255];
}

// Chunk-serial single-block scan of bsums -> bpre; writes total + vnum.
__global__ void k_scan2(const int* bsums, int* bpre, int nb, int* total, float* out) {
    __shared__ int sh[256];
    int t = threadIdx.x;
    int C = (nb + 255) / 256;
    int lo = t * C;
    int hi = lo + C < nb ? lo + C : nb;
    int s = 0;
    for (int i = lo; i < hi; i++) s += bsums[i];
    sh[t] = s;
    __syncthreads();
    for (int off = 1; off < 256; off <<= 1) {
        int xv = (t >= off) ? sh[t - off] : 0;
        __syncthreads();
        sh[t] += xv;
        __syncthreads();
    }
    int run = sh[t] - s;
    for (int i = lo; i < hi; i++) { bpre[i] = run; run += bsums[i]; }
    if (t == 255) {
        int T = sh[255];
        *total = T;
        if (T > MAXV) T = MAXV;
        out[OUT_VNUM] = bfround((float)T);
    }
}

// Blocks [0,nb): firsts[v] = (key<<32)|i for first-occurrence points with
// v<MAXV (keys[] read, no recompute). Blocks [nb,nb+neb): bucket extras
// segments (16 records/bucket, 16 buckets/block). Blocks beyond: overflow.
__global__ void k_assign(const int* keys, int N,
                         const u8* flags, const u8* prefix, const int* bpre,
                         const u64* extras, const u32* ebcount,
                         const u64* ovf, const u32* ocount,
                         int nb, int neb,
                         u64* firsts, int* cnt, int* lists) {
    int b = blockIdx.x;
    int t = threadIdx.x;
    u64 rec;
    if (b < nb) {
        int i = b * 256 + t;
        if (i < N && flags[i]) {
            int v = (int)prefix[i] + bpre[i >> 8];
            if (v < MAXV)
                firsts[v] = ((u64)(u32)keys[i] << 32) | (u32)i;
        }
        return;
    } else if (b < nb + neb) {
        int r = (b - nb) * 256 + t;
        int br = r >> 4;          // SEGC == 16
        int sl = r & (SEGC - 1);
        if (br >= NBUCK) return;
        u32 c = ebcount[br];
        if (c > SEGC) c = SEGC;
        if ((u32)sl >= c) return;
        rec = extras[(size_t)br * SEGC + sl];
    } else {
        u32 j2 = (u32)(b - nb - neb) * 256 + t;
        u32 oc = *ocount;
        if (oc > OCAP) oc = OCAP;
        if (j2 >= oc) return;
        rec = ovf[j2];
    }
    u32 f = (u32)(rec >> 32);
    u32 pidx = (u32)rec;
    int v = (int)prefix[f] + bpre[f >> 8];
    if (v >= MAXV) return;
    int pos = atomicAdd(&cnt[v], 1);
    if (pos < LCAP) lists[v * LCAP + pos] = (int)pidx;
}

// Sole output writer (d_out is poisoned each call): per v writes the full
// 10x5 voxel block, coors (coalesced in v), npv.
__global__ void k_write(const void* pts, const int* dflag, const u64* firsts,
                        const int* cnt, const int* lists, const int* total,
                        float* out) {
    int v = blockIdx.x * blockDim.x + threadIdx.x;
    if (v >= MAXV) return;
    int T = *total;
    if (T > MAXV) T = MAXV;
    float* dst = out + (size_t)v * MAXP * 5;
    if (v >= T) {
        for (int j = 0; j < MAXP * 5; j++) dst[j] = 0.0f;
        out[OUT_COORS + v * 3 + 0] = -1.0f;
        out[OUT_COORS + v * 3 + 1] = -1.0f;
        out[OUT_COORS + v * 3 + 2] = -1.0f;
        out[OUT_NPV + v] = 0.0f;
        return;
    }
    u64 fe = firsts[v];
    u32 key = (u32)(fe >> 32);
    int f = (int)(u32)fe;
    int cx = (int)(key % GXC);
    u32 r = key / GXC;
    int cy = (int)(r % GYC);
    int cz = (int)(r / GYC);
    out[OUT_COORS + v * 3 + 0] = bfround((float)cz);
    out[OUT_COORS + v * 3 + 1] = bfround((float)cy);
    out[OUT_COORS + v * 3 + 2] = bfround((float)cx);
    int c = cnt[v];
    int np = 1 + c;
    if (np > MAXP) np = MAXP;
    out[OUT_NPV + v] = (float)np;
    int bf = *dflag;
    for (int j = 0; j < 5; j++) dst[j] = bfround(load_ch(pts, f, j, bf));
    if (c > 0) {
        int m = (c < LCAP) ? c : LCAP;
        int idx[LCAP];
        for (int j = 0; j < m; j++) idx[j] = lists[v * LCAP + j];
        for (int a = 1; a < m; a++) {  // sort dup indices -> insertion order
            int kk = idx[a];
            int b2 = a - 1;
            while (b2 >= 0 && idx[b2] > kk) { idx[b2 + 1] = idx[b2]; b2--; }
            idx[b2 + 1] = kk;
        }
        for (int rr = 1; rr < np; rr++) {
            int p = idx[rr - 1];
            for (int j = 0; j < 5; j++)
                dst[rr * 5 + j] = bfround(load_ch(pts, p, j, bf));
        }
    }
    for (int rr = np; rr < MAXP; rr++)
        for (int j = 0; j < 5; j++) dst[rr * 5 + j] = 0.0f;
}

extern "C" void kernel_launch(void* const* d_in, const int* in_sizes, int n_in,
                              void* d_out, int out_size, void* d_ws, size_t ws_size,
                              hipStream_t stream) {
    (void)n_in; (void)out_size;
    const void* pts = d_in[0];
    int N = in_sizes[0] / 5;
    float* out = (float*)d_out;
    if (N <= 0 || N > 16384 * 256) return;

    int nb = (N + 255) / 256;
    size_t npad = ((size_t)N + 255) & ~(size_t)255;

    // ws: keys[npad]*4 | flags[npad] | prefix[npad] | bsums/bpre[16384]*4 |
    //     total dflag ocount | firsts[MAXV]*8 | cnt[MAXV]*4 |
    //     lists[MAXV*LCAP]*4 | hist/bstart/fill[MSUB]*4 |
    //     extras[NBUCK*SEGC]*8 | ovf[OCAP]*8 | pairs[npad]*8 | ebcount[NBUCK]*4
    size_t need = npad * 4 + npad + npad + 16384 * 8 + 512
                + (size_t)MAXV * 8 + (size_t)MAXV * 4 + (size_t)MAXV * LCAP * 4
                + (size_t)MSUB * 4 * 3
                + (size_t)NBUCK * SEGC * 8 + (size_t)OCAP * 8
                + npad * 8 + (size_t)NBUCK * 4;   // ~39.9 MB
    if (ws_size < need) return;

    char* w = (char*)d_ws;
    int* keys   = (int*)w;  w += npad * 4;
    u8*  flags  = (u8*)w;   w += npad;
    u8*  prefix = (u8*)w;   w += npad;
    int* bsums  = (int*)w;  w += 16384 * 4;
    int* bpre   = (int*)w;  w += 16384 * 4;
    int* total  = (int*)w;  w += 128;
    int* dflag  = (int*)w;  w += 128;
    u32* ocount = (u32*)w;  w += 256;
    u64* firsts = (u64*)w;  w += (size_t)MAXV * 8;
    int* cnt    = (int*)w;  w += (size_t)MAXV * 4;
    int* lists  = (int*)w;  w += (size_t)MAXV * LCAP * 4;
    u32* hist   = (u32*)w;  w += (size_t)MSUB * 4;
    u32* bstart = (u32*)w;  w += (size_t)MSUB * 4;
    u32* fill   = (u32*)w;  w += (size_t)MSUB * 4;
    u64* extras = (u64*)w;  w += (size_t)NBUCK * SEGC * 8;
    u64* ovf    = (u64*)w;  w += (size_t)OCAP * 8;
    u64* pairs  = (u64*)w;  w += npad * 8;
    u32* ebcount= (u32*)w;

    int neb = (NBUCK * SEGC + 255) / 256;  // 691 extras blocks

    k_init<<<1024, 256, 0, stream>>>(hist, cnt, N, (const u16*)pts,
                                     dflag, ocount, total);
    Voxelization_87136296501765_kernel<<<nb, 256, 0, stream>>>(
        pts, N, dflag, keys, flags, hist);
    k_scanB<<<1, 1024, 0, stream>>>(hist, bstart, fill);
    k_bin2<<<nb, 256, 0, stream>>>(keys, N, fill, pairs);
    k_dedup<<<NBUCK, 256, 0, stream>>>(pairs, bstart, hist, flags,
                                       extras, ebcount, ovf, ocount);
    k_scan1<<<nb, 256, 0, stream>>>(flags, prefix, bsums, N);
    k_scan2<<<1, 256, 0, stream>>>(bsums, bpre, nb, total, out);
    k_assign<<<nb + neb + OCAP / 256, 256, 0, stream>>>(
        keys, N, flags, prefix, bpre, extras, ebcount, ovf, ocount,
        nb, neb, firsts, cnt, lists);
    k_write<<<(MAXV + 255) / 256, 256, 0, stream>>>(pts, dflag, firsts, cnt,
                                                    lists, total, out);
}

// Round 2
// 410.044 us; speedup vs baseline: 1.5218x; 1.5218x over previous
//

#include <hip/hip_runtime.h>
#include <hip/hip_bf16.h>

// Deterministic hard_voxelize. Round 17: keep R16's bucketed LDS dedup
// (no global hash table), fix R16's fatal flaw: k_scanB was a single-block
// chunk-serial scan -> 64 distinct 64B lines per wave-load -> single-CU
// transaction bound (192us @ 4.6GB/s). All scans are now hierarchical,
// multi-block, coalesced:
//   scanB1/2/3 : 346-block scan of padded sub-segment counts -> fill
//   scan2a/2b  : 2-level scan of per-block first-counts (add folded into
//                k_assign as bpre + b2pre)
// Pair segments are 64B-aligned so each (bucket,shard=blockIdx&7~XCD)
// segment's lines are written by one XCD only -> full-line writebacks.
// k_assign: blocks with base rank >= MAXV exit before touching flags/prefix.
// Measured laws: scattered 64B-line RMW ~1.45TB/s; single-CU uncoalesced
// access ~1 line-transaction/cycle (R16 post-mortem); hot-line atomics ~7ns.

#define MAXV 150000
#define MAXP 10
#define LCAP 12
#define GXC 1504
#define GYC 1504
#define GZC 40

#define BSHIFT 13
#define BSIZE (1 << BSHIFT)      // 8192 keys per bucket, 32KB LDS table
#define NBUCK 11045              // 1504*1504*40 / 8192 exactly
#define NSHARD 8
#define MSUB (NBUCK * NSHARD)    // 88360 sub-segments
#define SB1B ((MSUB + 255) / 256)  // 346 scanB1 blocks
#define SEGC 16                  // extras segment per bucket (avg ~5 dups)
#define OCAP (1 << 15)           // global overflow (adversarial only)

#define OUT_COORS 7500000
#define OUT_NPV   7950000
#define OUT_VNUM  8100000

typedef unsigned char u8;
typedef unsigned short u16;
typedef unsigned int u32;
typedef unsigned long long u64;

__device__ __forceinline__ u16 f2bf(float v) {  // round-to-nearest-even
    u32 b = __float_as_uint(v);
    return (u16)((b + 0x7FFFu + ((b >> 16) & 1u)) >> 16);
}
__device__ __forceinline__ float bf2f(u16 u) {
    return __uint_as_float(((u32)u) << 16);
}
__device__ __forceinline__ float bfround(float v) { return bf2f(f2bf(v)); }

// Init (+ fused dtype detect in block 0): hist=0, cnt=0, counters=0.
__global__ void k_init(u32* hist, int* cnt, int N, const u16* raw,
                       int* dflag, u32* ocount, int* total) {
    if (blockIdx.x == 0) {
        __shared__ int v32;
        __shared__ int v16;
        if (threadIdx.x == 0) { v32 = 0; v16 = 0; }
        __syncthreads();
        int r = (int)threadIdx.x * 37;
        if (r >= N) r = N > 0 ? N - 1 : 0;
        const float* p32 = (const float*)raw;
        float a3 = p32[r * 5 + 3];
        float a4 = p32[r * 5 + 4];
        float b3 = bf2f(raw[r * 5 + 3]);
        float b4 = bf2f(raw[r * 5 + 4]);
        int ok32 = (a3 == a3) && (a4 == a4) &&
                   (a3 >= -0.001f) && (a3 <= 1.001f) && (a4 >= -0.001f) && (a4 <= 1.001f);
        int okbf = (b3 == b3) && (b4 == b4) &&
                   (b3 >= -0.001f) && (b3 <= 1.001f) && (b4 >= -0.001f) && (b4 <= 1.001f);
        if (ok32) atomicAdd(&v32, 1);
        if (okbf) atomicAdd(&v16, 1);
        __syncthreads();
        if (threadIdx.x == 0) *dflag = (v16 > v32) ? 1 : 0;
    }
    int stride = gridDim.x * blockDim.x;
    int i0 = blockIdx.x * blockDim.x + threadIdx.x;
    for (int i = i0; i < MSUB; i += stride) hist[i] = 0u;
    for (int i = i0; i < MAXV; i += stride) cnt[i] = 0;
    if (i0 == 0) { *ocount = 0u; *total = 0; }
}

__device__ __forceinline__ float load_ch(const void* pts, int i, int j, int bf) {
    if (bf) return bf2f(((const u16*)pts)[i * 5 + j]);
    return ((const float*)pts)[i * 5 + j];
}

// Exact f32 sub+div+floor, matching reference arithmetic. -1 if out of range.
__device__ __forceinline__ int point_key(const void* pts, int i, int bf) {
    float x = load_ch(pts, i, 0, bf);
    float y = load_ch(pts, i, 1, bf);
    float z = load_ch(pts, i, 2, bf);
    int cx = (int)floorf((x - (-75.2f)) / 0.1f);
    int cy = (int)floorf((y - (-75.2f)) / 0.1f);
    int cz = (int)floorf((z - (-2.0f)) / 0.15f);
    if (cx < 0 || cx >= GXC || cy < 0 || cy >= GYC || cz < 0 || cz >= GZC) return -1;
    return (cz * GYC + cy) * GXC + cx;
}

// Canonical kernel: one coalesced points pass -> keys, flags, sharded bucket
// histogram. Shard = blockIdx&7 (~XCD under round-robin dispatch; matches
// bin2's formula so per-sub-segment counts are exact).
__global__ void Voxelization_87136296501765_kernel(
        const void* pts, int N, const int* dflag,
        int* keys, u8* flags, u32* hist) {
    int i = blockIdx.x * 256 + threadIdx.x;
    if (i >= N) return;
    int key = point_key(pts, i, *dflag);
    keys[i] = key;
    flags[i] = (u8)(key >= 0);
    if (key >= 0)
        atomicAdd(&hist[((u32)key >> BSHIFT) * NSHARD + (blockIdx.x & (NSHARD - 1))], 1u);
}

// Hierarchical coalesced scan of 64B-padded sub-segment counts.
// pc[j] = (hist[j]+7)&~7 so every segment start is 64B-aligned -> each
// segment's pair lines are written by a single shard (~XCD).
__global__ void k_scanB1(const u32* hist, u32* ppre, u32* pbsums) {
    __shared__ u32 sh[256];
    int t = threadIdx.x;
    int j = blockIdx.x * 256 + t;
    u32 v = 0;
    if (j < MSUB) v = (hist[j] + 7u) & ~7u;
    sh[t] = v;
    __syncthreads();
    for (int off = 1; off < 256; off <<= 1) {
        u32 x = (t >= off) ? sh[t - off] : 0u;
        __syncthreads();
        sh[t] += x;
        __syncthreads();
    }
    if (j < MSUB) ppre[j] = sh[t] - v;
    if (t == 255) pbsums[blockIdx.x] = sh[255];
}

__global__ void k_scanB2(const u32* pbsums, u32* pbpre) {
    __shared__ u32 sh[512];
    int t = threadIdx.x;
    u32 v = (t < SB1B) ? pbsums[t] : 0u;
    sh[t] = v;
    __syncthreads();
    for (int off = 1; off < 512; off <<= 1) {
        u32 x = (t >= off) ? sh[t - off] : 0u;
        __syncthreads();
        sh[t] += x;
        __syncthreads();
    }
    if (t < SB1B) pbpre[t] = sh[t] - v;
}

__global__ void k_scanB3(const u32* ppre, const u32* pbpre, u32* fill) {
    int j = blockIdx.x * 256 + threadIdx.x;
    if (j < MSUB) fill[j] = ppre[j] + pbpre[j >> 8];
}

// Scatter (key, idx) pairs into exact 64B-aligned per-(bucket,shard) segments.
__global__ void k_bin2(const int* keys, int N, u32* fill, u64* pairs) {
    int i = blockIdx.x * 256 + threadIdx.x;
    if (i >= N) return;
    int key = keys[i];
    if (key < 0) return;
    int j = (int)(((u32)key >> BSHIFT) * NSHARD) + (blockIdx.x & (NSHARD - 1));
    u32 pos = atomicAdd(&fill[j], 1u);
    pairs[pos] = ((u64)(u32)key << 32) | (u32)i;
}

// Per-bucket LDS direct-map dedup. tabs[key&8191] = min point idx (= first
// occurrence; within a bucket key&8191 is unique so no collisions).
// Second pass: dup iff idx != min -> clear flag, emit resolved (f, pidx).
__global__ void __launch_bounds__(256) k_dedup(
        const u64* pairs, const u32* ppre, const u32* pbpre, const u32* hist,
        u8* flags, u64* extras, u32* ebcount, u64* ovf, u32* ocount) {
    __shared__ u32 tabs[BSIZE];
    __shared__ u32 s_cnt;
    int b = blockIdx.x;
    int base = b * NSHARD;
    u32 st[NSHARD], cc[NSHARD];
    u32 tot = 0;
#pragma unroll
    for (int s = 0; s < NSHARD; s++) {
        int j = base + s;
        st[s] = ppre[j] + pbpre[j >> 8];
        cc[s] = hist[j];
        tot += cc[s];
    }
    if (tot == 0) {
        if (threadIdx.x == 0) ebcount[b] = 0u;
        return;
    }
    uint4* t4 = (uint4*)tabs;
    for (int j = threadIdx.x; j < BSIZE / 4; j += 256)
        t4[j] = make_uint4(0xFFFFFFFFu, 0xFFFFFFFFu, 0xFFFFFFFFu, 0xFFFFFFFFu);
    if (threadIdx.x == 0) s_cnt = 0u;
    __syncthreads();
#pragma unroll
    for (int s = 0; s < NSHARD; s++) {
        u32 c = cc[s], stt = st[s];
        for (u32 j = threadIdx.x; j < c; j += 256) {
            u64 pr = pairs[stt + j];
            atomicMin(&tabs[(u32)(pr >> 32) & (BSIZE - 1)], (u32)pr);
        }
    }
    __syncthreads();
#pragma unroll
    for (int s = 0; s < NSHARD; s++) {
        u32 c = cc[s], stt = st[s];
        for (u32 j = threadIdx.x; j < c; j += 256) {
            u64 pr = pairs[stt + j];
            u32 i = (u32)pr;
            u32 f = tabs[(u32)(pr >> 32) & (BSIZE - 1)];
            if (f != i) {
                flags[i] = 0;
                u64 rec = ((u64)f << 32) | i;
                u32 pos = atomicAdd(&s_cnt, 1u);
                if (pos < SEGC) {
                    extras[(size_t)b * SEGC + pos] = rec;
                } else {
                    u32 op = atomicAdd(ocount, 1u);  // adversarial only
                    if (op < OCAP) ovf[op] = rec;
                }
            }
        }
    }
    __syncthreads();
    if (threadIdx.x == 0) ebcount[b] = s_cnt;
}

// flags -> prefix (separate array; flags preserved for k_assign) + bsums.
__global__ void k_scan1(const u8* flags, u8* prefix, int* bsums, int n) {
    __shared__ int sh[256];
    int t = threadIdx.x;
    int i = blockIdx.x * 256 + t;
    int v = (i < n) ? (int)flags[i] : 0;
    sh[t] = v;
    __syncthreads();
    for (int off = 1; off < 256; off <<= 1) {
        int xv = (t >= off) ? sh[t - off] : 0;
        __syncthreads();
        sh[t] += xv;
        __syncthreads();
    }
    if (i < n) prefix[i] = (u8)(sh[t] - v);
    if (t == 255) bsums[blockIdx.x] = sh[255];
}

// 2-level scan of bsums (coalesced, multi-block). Final add folded into
// k_assign as bpre[i>>8] + b2pre[i>>16].
__global__ void k_scan2a(const int* bsums, int nb, int* bpre, int* b2sums) {
    __shared__ int sh[256];
    int t = threadIdx.x;
    int i = blockIdx.x * 256 + t;
    int v = (i < nb) ? bsums[i] : 0;
    sh[t] = v;
    __syncthreads();
    for (int off = 1; off < 256; off <<= 1) {
        int xv = (t >= off) ? sh[t - off] : 0;
        __syncthreads();
        sh[t] += xv;
        __syncthreads();
    }
    if (i < nb) bpre[i] = sh[t] - v;
    if (t == 255) b2sums[blockIdx.x] = sh[255];
}

__global__ void k_scan2b(const int* b2sums, int nb2, int* b2pre,
                         int* total, float* out) {
    __shared__ int sh[64];
    int t = threadIdx.x;  // 64 threads
    int v = (t < nb2) ? b2sums[t] : 0;
    sh[t] = v;
    __syncthreads();
    for (int off = 1; off < 64; off <<= 1) {
        int xv = (t >= off) ? sh[t - off] : 0;
        __syncthreads();
        sh[t] += xv;
        __syncthreads();
    }
    if (t < nb2) b2pre[t] = sh[t] - v;
    if (t == 63) {
        int T = sh[63];
        *total = T;
        if (T > MAXV) T = MAXV;
        out[OUT_VNUM] = bfround((float)T);
    }
}

// Blocks [0,nb): firsts[v] = (key<<32)|i for first-occurrence points with
// v<MAXV. v monotone in i -> blocks whose base rank >= MAXV exit early
// (92% of blocks touch nothing). Blocks [nb,nb+neb): bucket extras
// segments. Beyond: overflow records.
__global__ void k_assign(const int* keys, int N,
                         const u8* flags, const u8* prefix,
                         const int* bpre, const int* b2pre,
                         const u64* extras, const u32* ebcount,
                         const u64* ovf, const u32* ocount,
                         int nb, int neb,
                         u64* firsts, int* cnt, int* lists) {
    int b = blockIdx.x;
    int t = threadIdx.x;
    u64 rec;
    if (b < nb) {
        int vbase = bpre[b] + b2pre[b >> 8];
        if (vbase >= MAXV) return;  // whole block beyond cap
        int i = b * 256 + t;
        if (i < N && flags[i]) {
            int v = (int)prefix[i] + vbase;
            if (v < MAXV)
                firsts[v] = ((u64)(u32)keys[i] << 32) | (u32)i;
        }
        return;
    } else if (b < nb + neb) {
        int r = (b - nb) * 256 + t;
        int br = r >> 4;          // SEGC == 16
        int sl = r & (SEGC - 1);
        if (br >= NBUCK) return;
        u32 c = ebcount[br];
        if (c > SEGC) c = SEGC;
        if ((u32)sl >= c) return;
        rec = extras[(size_t)br * SEGC + sl];
    } else {
        u32 j2 = (u32)(b - nb - neb) * 256 + t;
        u32 oc = *ocount;
        if (oc > OCAP) oc = OCAP;
        if (j2 >= oc) return;
        rec = ovf[j2];
    }
    u32 f = (u32)(rec >> 32);
    u32 pidx = (u32)rec;
    int vb = bpre[f >> 8] + b2pre[f >> 16];
    if (vb >= MAXV) return;       // voxel beyond cap, skip prefix read
    int v = (int)prefix[f] + vb;
    if (v >= MAXV) return;
    int pos = atomicAdd(&cnt[v], 1);
    if (pos < LCAP) lists[v * LCAP + pos] = (int)pidx;
}

// Sole output writer (d_out is poisoned each call): per v writes the full
// 10x5 voxel block, coors (coalesced in v), npv.
__global__ void k_write(const void* pts, const int* dflag, const u64* firsts,
                        const int* cnt, const int* lists, const int* total,
                        float* out) {
    int v = blockIdx.x * blockDim.x + threadIdx.x;
    if (v >= MAXV) return;
    int T = *total;
    if (T > MAXV) T = MAXV;
    float* dst = out + (size_t)v * MAXP * 5;
    if (v >= T) {
        for (int j = 0; j < MAXP * 5; j++) dst[j] = 0.0f;
        out[OUT_COORS + v * 3 + 0] = -1.0f;
        out[OUT_COORS + v * 3 + 1] = -1.0f;
        out[OUT_COORS + v * 3 + 2] = -1.0f;
        out[OUT_NPV + v] = 0.0f;
        return;
    }
    u64 fe = firsts[v];
    u32 key = (u32)(fe >> 32);
    int f = (int)(u32)fe;
    int cx = (int)(key % GXC);
    u32 r = key / GXC;
    int cy = (int)(r % GYC);
    int cz = (int)(r / GYC);
    out[OUT_COORS + v * 3 + 0] = bfround((float)cz);
    out[OUT_COORS + v * 3 + 1] = bfround((float)cy);
    out[OUT_COORS + v * 3 + 2] = bfround((float)cx);
    int c = cnt[v];
    int np = 1 + c;
    if (np > MAXP) np = MAXP;
    out[OUT_NPV + v] = (float)np;
    int bf = *dflag;
    for (int j = 0; j < 5; j++) dst[j] = bfround(load_ch(pts, f, j, bf));
    if (c > 0) {
        int m = (c < LCAP) ? c : LCAP;
        int idx[LCAP];
        for (int j = 0; j < m; j++) idx[j] = lists[v * LCAP + j];
        for (int a = 1; a < m; a++) {  // sort dup indices -> insertion order
            int kk = idx[a];
            int b2 = a - 1;
            while (b2 >= 0 && idx[b2] > kk) { idx[b2 + 1] = idx[b2]; b2--; }
            idx[b2 + 1] = kk;
        }
        for (int rr = 1; rr < np; rr++) {
            int p = idx[rr - 1];
            for (int j = 0; j < 5; j++)
                dst[rr * 5 + j] = bfround(load_ch(pts, p, j, bf));
        }
    }
    for (int rr = np; rr < MAXP; rr++)
        for (int j = 0; j < 5; j++) dst[rr * 5 + j] = 0.0f;
}

extern "C" void kernel_launch(void* const* d_in, const int* in_sizes, int n_in,
                              void* d_out, int out_size, void* d_ws, size_t ws_size,
                              hipStream_t stream) {
    (void)n_in; (void)out_size;
    const void* pts = d_in[0];
    int N = in_sizes[0] / 5;
    float* out = (float*)d_out;
    if (N <= 0 || N > 16384 * 256) return;

    int nb = (N + 255) / 256;
    int nb2 = (nb + 255) / 256;                 // <= 64
    size_t npad = ((size_t)N + 255) & ~(size_t)255;
    size_t pairs_cap = npad + (size_t)7 * MSUB + 64;  // 64B-aligned segments

    // ws: keys[npad]*4 | flags[npad] | prefix[npad] | bsums/bpre[16384]*4 |
    //     b2sums/b2pre[64]*4 | total dflag ocount | firsts[MAXV]*8 |
    //     cnt[MAXV]*4 | lists[MAXV*LCAP]*4 | hist/ppre/fill[MSUB]*4 |
    //     pbsums/pbpre[512]*4 | extras[NBUCK*SEGC]*8 | ebcount | ovf[OCAP]*8 |
    //     pairs[pairs_cap]*8                       (~44.8 MB at N=2M)
    size_t need = npad * 4 + npad + npad + 16384 * 8 + 512 + 512
                + (size_t)MAXV * 8 + (size_t)MAXV * 4 + (size_t)MAXV * LCAP * 4
                + (size_t)MSUB * 4 * 3 + 4096
                + (size_t)NBUCK * SEGC * 8 + (size_t)NBUCK * 4 + 256
                + (size_t)OCAP * 8 + pairs_cap * 8;
    if (ws_size < need) return;

    char* w = (char*)d_ws;
    int* keys   = (int*)w;  w += npad * 4;
    u8*  flags  = (u8*)w;   w += npad;
    u8*  prefix = (u8*)w;   w += npad;
    int* bsums  = (int*)w;  w += 16384 * 4;
    int* bpre   = (int*)w;  w += 16384 * 4;
    int* b2sums = (int*)w;  w += 256;
    int* b2pre  = (int*)w;  w += 256;
    int* total  = (int*)w;  w += 128;
    int* dflag  = (int*)w;  w += 128;
    u32* ocount = (u32*)w;  w += 256;
    u64* firsts = (u64*)w;  w += (size_t)MAXV * 8;
    int* cnt    = (int*)w;  w += (size_t)MAXV * 4;
    int* lists  = (int*)w;  w += (size_t)MAXV * LCAP * 4;
    u32* hist   = (u32*)w;  w += (size_t)MSUB * 4;
    u32* ppre   = (u32*)w;  w += (size_t)MSUB * 4;
    u32* fill   = (u32*)w;  w += (size_t)MSUB * 4;
    u32* pbsums = (u32*)w;  w += 512 * 4;
    u32* pbpre  = (u32*)w;  w += 512 * 4;
    u64* extras = (u64*)w;  w += (size_t)NBUCK * SEGC * 8;
    u32* ebcount= (u32*)w;  w += ((size_t)NBUCK * 4 + 255) & ~(size_t)255;
    u64* ovf    = (u64*)w;  w += (size_t)OCAP * 8;
    u64* pairs  = (u64*)w;

    int neb = (NBUCK * SEGC + 255) / 256;  // 691 extras blocks

    k_init<<<1024, 256, 0, stream>>>(hist, cnt, N, (const u16*)pts,
                                     dflag, ocount, total);
    Voxelization_87136296501765_kernel<<<nb, 256, 0, stream>>>(
        pts, N, dflag, keys, flags, hist);
    k_scanB1<<<SB1B, 256, 0, stream>>>(hist, ppre, pbsums);
    k_scanB2<<<1, 512, 0, stream>>>(pbsums, pbpre);
    k_scanB3<<<SB1B, 256, 0, stream>>>(ppre, pbpre, fill);
    k_bin2<<<nb, 256, 0, stream>>>(keys, N, fill, pairs);
    k_dedup<<<NBUCK, 256, 0, stream>>>(pairs, ppre, pbpre, hist, flags,
                                       extras, ebcount, ovf, ocount);
    k_scan1<<<nb, 256, 0, stream>>>(flags, prefix, bsums, N);
    k_scan2a<<<nb2, 256, 0, stream>>>(bsums, nb, bpre, b2sums);
    k_scan2b<<<1, 64, 0, stream>>>(b2sums, nb2, b2pre, total, out);
    k_assign<<<nb + neb + OCAP / 256, 256, 0, stream>>>(
        keys, N, flags, prefix, bpre, b2pre, extras, ebcount, ovf, ocount,
        nb, neb, firsts, cnt, lists);
    k_write<<<(MAXV + 255) / 256, 256, 0, stream>>>(pts, dflag, firsts, cnt,
                                                    lists, total, out);
}

// Round 3
// 203.621 us; speedup vs baseline: 3.0645x; 2.0138x over previous
//

#include <hip/hip_runtime.h>
#include <hip/hip_bf16.h>

// Deterministic hard_voxelize. Round 18: kill the 2M-point partition entirely.
// R17 post-mortem: k_bin2 (174us, 87MB writes @512GB/s) = returning atomicAdd
// on contended counter lines + dependent 8B scatter into cross-XCD-shared
// tail lines. Any full-N grouping pays this. But the kept-voxel set (vid <
// 150K) is determined by the first ~154K points (distinct(262144) ~= 261K >>
// 150K for uniform input). New structure:
//   prefix [0,256K): split-array hash insert (tkey u32 CAS-claim + tidx u32
//     atomicMin by point idx = first occurrence). 256K scattered RMW into
//     4MB ~= 12-16us (R15 law 2M->124us, scaled). Rank/assign on 1024 blocks.
//   suffix [256K,N): READ-ONLY probes of the 2MB tkey (L2-cached, replicated
//     per XCD, no coherence traffic); ~0.4% hits -> ~7K dup atomics.
//   fallback (distinct(prefix) < MAXV; never on bench input): device-gated
//     full re-run with packed-u64 16.8MB table; gated kernels cost only
//     empty-dispatch overhead.
// Measured laws: scattered 64B RMW ~1.45TB/s; returning-atomic+scatter chains
// ~0.5TB/s (R17); fire-and-forget atomics pipeline freely; single-CU serial
// scans are transaction-bound (R16).

#define MAXV 150000
#define MAXP 10
#define LCAP 12
#define GXC 1504
#define GYC 1504
#define GZC 40

#define PPREF 262144           // prefix length (1024 blocks)
#define HC 19
#define HCAP (1u << HC)        // 524288 slots; load <= 0.5 at P=256K
#define HMASK (HCAP - 1u)
#define FHCAP (1u << 21)       // fallback packed table (16.8MB), gated only
#define FHMASK (FHCAP - 1u)
#define SEGC 16                // extras segment per block
#define OCAP (1 << 15)         // global overflow (adversarial only)

#define OUT_COORS 7500000
#define OUT_NPV   7950000
#define OUT_VNUM  8100000
#define EMPTY64 0xFFFFFFFFFFFFFFFFULL

typedef unsigned char u8;
typedef unsigned short u16;
typedef unsigned int u32;
typedef unsigned long long u64;

__device__ __forceinline__ u16 f2bf(float v) {  // round-to-nearest-even
    u32 b = __float_as_uint(v);
    return (u16)((b + 0x7FFFu + ((b >> 16) & 1u)) >> 16);
}
__device__ __forceinline__ float bf2f(u16 u) {
    return __uint_as_float(((u32)u) << 16);
}
__device__ __forceinline__ float bfround(float v) { return bf2f(f2bf(v)); }

__device__ __forceinline__ u32 hslot(int key) {
    return (((u32)key * 2654435761u) >> 12) & HMASK;
}
__device__ __forceinline__ u32 fhslot(int key) {
    return (((u32)key * 2654435761u) >> 10) & FHMASK;
}

// Init (+ fused dtype detect in block 0): tkey=0, tidx=FFFF, cnt=0, scalars.
__global__ void k_init(u32* tkey, u32* tidx, int* cnt, int N, const u16* raw,
                       int* dflag, u32* ocount, int* total, int* fastflag) {
    if (blockIdx.x == 0) {
        __shared__ int v32;
        __shared__ int v16;
        if (threadIdx.x == 0) { v32 = 0; v16 = 0; }
        __syncthreads();
        int r = (int)threadIdx.x * 37;
        if (r >= N) r = N > 0 ? N - 1 : 0;
        const float* p32 = (const float*)raw;
        float a3 = p32[r * 5 + 3];
        float a4 = p32[r * 5 + 4];
        float b3 = bf2f(raw[r * 5 + 3]);
        float b4 = bf2f(raw[r * 5 + 4]);
        int ok32 = (a3 == a3) && (a4 == a4) &&
                   (a3 >= -0.001f) && (a3 <= 1.001f) && (a4 >= -0.001f) && (a4 <= 1.001f);
        int okbf = (b3 == b3) && (b4 == b4) &&
                   (b3 >= -0.001f) && (b3 <= 1.001f) && (b4 >= -0.001f) && (b4 <= 1.001f);
        if (ok32) atomicAdd(&v32, 1);
        if (okbf) atomicAdd(&v16, 1);
        __syncthreads();
        if (threadIdx.x == 0) *dflag = (v16 > v32) ? 1 : 0;
    }
    int stride = gridDim.x * blockDim.x;
    int i0 = blockIdx.x * blockDim.x + threadIdx.x;
    for (u32 i = (u32)i0; i < HCAP; i += (u32)stride) {
        tkey[i] = 0u;
        tidx[i] = 0xFFFFFFFFu;
    }
    for (int i = i0; i < MAXV; i += stride) cnt[i] = 0;
    if (i0 == 0) { *ocount = 0u; *total = 0; *fastflag = 0; }
}

__device__ __forceinline__ float load_ch(const void* pts, int i, int j, int bf) {
    if (bf) return bf2f(((const u16*)pts)[i * 5 + j]);
    return ((const float*)pts)[i * 5 + j];
}

// Exact f32 sub+div+floor, matching reference arithmetic. -1 if out of range.
__device__ __forceinline__ int point_key(const void* pts, int i, int bf) {
    float x = load_ch(pts, i, 0, bf);
    float y = load_ch(pts, i, 1, bf);
    float z = load_ch(pts, i, 2, bf);
    int cx = (int)floorf((x - (-75.2f)) / 0.1f);
    int cy = (int)floorf((y - (-75.2f)) / 0.1f);
    int cz = (int)floorf((z - (-2.0f)) / 0.15f);
    if (cx < 0 || cx >= GXC || cy < 0 || cy >= GYC || cz < 0 || cz >= GZC) return -1;
    return (cz * GYC + cy) * GXC + cx;
}

// Canonical kernel: one coalesced all-points pass -> keys, flags. No atomics.
__global__ void Voxelization_87136296501765_kernel(
        const void* pts, int N, const int* dflag, int* keys, u8* flags) {
    int i = blockIdx.x * 256 + threadIdx.x;
    if (i >= N) return;
    int key = point_key(pts, i, *dflag);
    keys[i] = key;
    flags[i] = (u8)(key >= 0);
}

// Prefix hash insert: CAS-claim tkey (key+1), atomicMin tidx by point idx.
// Emission rule per atomicMin linearization: old==FFFF -> none; old<i -> emit
// i (self); old>i -> emit old (displaced). Emits each non-min point exactly
// once; clears its flag inline (single writer per emitted point).
__global__ void k_insert(const int* keys, int Peff, u32* tkey, u32* tidx,
                         u8* flags, u64* extras, u32* bcount,
                         u64* ovf, u32* ocount) {
    __shared__ u32 s_cnt;
    if (threadIdx.x == 0) s_cnt = 0;
    __syncthreads();
    int i = blockIdx.x * 256 + threadIdx.x;
    bool has = false;
    u32 eslot = 0, eidx = 0;
    if (i < Peff) {
        int key = keys[i];
        if (key >= 0) {
            u32 kk = (u32)key + 1u;
            u32 slot = hslot(key);
            for (u32 tries = 0; tries <= HMASK; ++tries) {
                u32 prev = atomicCAS(&tkey[slot], 0u, kk);
                if (prev == 0u || prev == kk) {
                    u32 old = atomicMin(&tidx[slot], (u32)i);
                    if (old != 0xFFFFFFFFu) {
                        eidx = (old > (u32)i) ? old : (u32)i;
                        eslot = slot;
                        has = true;
                        flags[eidx] = 0;
                    }
                    break;
                }
                slot = (slot + 1u) & HMASK;
            }
        }
    }
    if (has) {
        u32 pos = atomicAdd(&s_cnt, 1u);
        u64 rec = ((u64)eslot << 32) | eidx;
        if (pos < SEGC) {
            extras[(size_t)blockIdx.x * SEGC + pos] = rec;
        } else {
            u32 op = atomicAdd(ocount, 1u);
            if (op < OCAP) ovf[op] = rec;
        }
    }
    __syncthreads();
    if (threadIdx.x == 0) bcount[blockIdx.x] = s_cnt;
}

// flags -> per-block exclusive rank + block sums (range [0,n)).
__global__ void k_scan1(const u8* flags, u8* prefix, int* bsums, int n) {
    __shared__ int sh[256];
    int t = threadIdx.x;
    int i = blockIdx.x * 256 + t;
    int v = (i < n) ? (int)flags[i] : 0;
    sh[t] = v;
    __syncthreads();
    for (int off = 1; off < 256; off <<= 1) {
        int xv = (t >= off) ? sh[t - off] : 0;
        __syncthreads();
        sh[t] += xv;
        __syncthreads();
    }
    if (i < n) prefix[i] = (u8)(sh[t] - v);
    if (t == 255) bsums[blockIdx.x] = sh[255];
}

// Single-block scan of nbp (<=1024) block sums. Writes total, fastflag, vnum.
__global__ void k_scan2p(const int* bsums, int nbp, int* bpre,
                         int* total, int* fastflag, float* out) {
    __shared__ int sh[256];
    int t = threadIdx.x;
    int C = (nbp + 255) / 256;
    int lo = t * C;
    int hi = lo + C < nbp ? lo + C : nbp;
    int s = 0;
    for (int i = lo; i < hi; i++) s += bsums[i];
    sh[t] = s;
    __syncthreads();
    for (int off = 1; off < 256; off <<= 1) {
        int xv = (t >= off) ? sh[t - off] : 0;
        __syncthreads();
        sh[t] += xv;
        __syncthreads();
    }
    int run = sh[t] - s;
    for (int i = lo; i < hi; i++) { bpre[i] = run; run += bsums[i]; }
    if (t == 255) {
        int T = sh[255];
        *total = T;
        *fastflag = (T >= MAXV) ? 1 : 0;
        if (T > MAXV) T = MAXV;
        out[OUT_VNUM] = bfround((float)T);
    }
}

// Prefix assign: firsts[v] for flagged prefix points (v monotone in i ->
// coalesced); extras tail per block (f resolved via tidx[slot]); ovf blocks.
__global__ void k_assign_pre(const int* keys, int Peff, const u8* flags,
                             const u8* prefix, const int* bpre, const u32* tidx,
                             const u64* extras, const u32* bcount,
                             const u64* ovf, const u32* ocount, int nbp,
                             u64* firsts, int* cnt, int* lists) {
    int b = blockIdx.x;
    int t = threadIdx.x;
    u64 rec;
    if (b < nbp) {
        int i = b * 256 + t;
        int vbase = bpre[b];
        if (vbase < MAXV && i < Peff && flags[i]) {
            int v = (int)prefix[i] + vbase;
            if (v < MAXV)
                firsts[v] = ((u64)(u32)keys[i] << 32) | (u32)i;
        }
        u32 c = bcount[b];
        if (c > SEGC) c = SEGC;
        if ((u32)t >= c) return;
        rec = extras[(size_t)b * SEGC + t];
    } else {
        u32 j = (u32)(b - nbp) * 256 + t;
        u32 oc = *ocount;
        if (oc > OCAP) oc = OCAP;
        if (j >= oc) return;
        rec = ovf[j];
    }
    u32 slot = (u32)(rec >> 32);
    u32 pidx = (u32)rec;
    u32 f = tidx[slot];
    int v = (int)prefix[f] + bpre[f >> 8];
    if (v >= MAXV) return;
    int pos = atomicAdd(&cnt[v], 1);
    if (pos < LCAP) lists[v * LCAP + pos] = (int)pidx;
}

// Suffix lookup (fast path only): read-only probes of tkey; on hit, the
// voxel's first point f is in the prefix -> v from prefix ranks. ~0.4% hit.
__global__ void k_lookup(const int* keys, int N, int P, const int* fastflag,
                         const u32* tkey, const u32* tidx,
                         const u8* prefix, const int* bpre,
                         int* cnt, int* lists) {
    if (*fastflag == 0) return;
    int i = P + blockIdx.x * 256 + threadIdx.x;
    if (i >= N) return;
    int key = keys[i];
    if (key < 0) return;
    u32 kk = (u32)key + 1u;
    u32 slot = hslot(key);
    for (u32 tries = 0; tries <= HMASK; ++tries) {
        u32 e = tkey[slot];
        if (e == 0u) return;            // voxel not opened in prefix -> dropped
        if (e == kk) {
            u32 f = tidx[slot];
            int v = (int)prefix[f] + bpre[f >> 8];
            if (v < MAXV) {
                int pos = atomicAdd(&cnt[v], 1);
                if (pos < LCAP) lists[v * LCAP + pos] = i;
            }
            return;
        }
        slot = (slot + 1u) & HMASK;
    }
}

// ---- Fallback path (distinct(prefix) < MAXV; gated, never on bench) ----

__global__ void k_finit(const int* fastflag, u64* ftab, int* cnt, u32* ocount) {
    if (*fastflag) return;
    int stride = gridDim.x * blockDim.x;
    int i0 = blockIdx.x * blockDim.x + threadIdx.x;
    for (u32 i = (u32)i0; i < FHCAP; i += (u32)stride) ftab[i] = EMPTY64;
    for (int i = i0; i < MAXV; i += stride) cnt[i] = 0;
    if (i0 == 0) *ocount = 0u;
}

__global__ void k_finsert(const int* fastflag, const int* keys, int N,
                          u64* ftab, u8* flags, u64* extras, u32* bcount,
                          u64* ovf, u32* ocount) {
    if (*fastflag) return;
    __shared__ u32 s_cnt;
    if (threadIdx.x == 0) s_cnt = 0;
    __syncthreads();
    int i = blockIdx.x * 256 + threadIdx.x;
    bool has = false;
    u32 eslot = 0, eidx = 0;
    if (i < N) {
        int key = keys[i];
        if (key >= 0) {
            u64 mine = ((u64)(u32)key << 32) | (u32)i;
            u32 slot = fhslot(key);
            for (u32 tries = 0; tries <= FHMASK; ++tries) {
                u64 prev = atomicCAS(&ftab[slot], EMPTY64, mine);
                if (prev == EMPTY64) break;
                if ((u32)(prev >> 32) == (u32)key) {
                    u32 pm = (u32)prev;
                    if (pm > (u32)i) {
                        u64 old = atomicMin((u64*)&ftab[slot], mine);
                        u32 om = (u32)old;
                        eidx = (om > (u32)i) ? om : (u32)i;
                    } else {
                        eidx = (u32)i;
                    }
                    eslot = slot;
                    has = true;
                    flags[eidx] = 0;
                    break;
                }
                slot = (slot + 1u) & FHMASK;
            }
        }
    }
    if (has) {
        u32 pos = atomicAdd(&s_cnt, 1u);
        u64 rec = ((u64)eslot << 32) | eidx;
        if (pos < SEGC) {
            extras[(size_t)blockIdx.x * SEGC + pos] = rec;
        } else {
            u32 op = atomicAdd(ocount, 1u);
            if (op < OCAP) ovf[op] = rec;
        }
    }
    __syncthreads();
    if (threadIdx.x == 0) bcount[blockIdx.x] = s_cnt;
}

__global__ void k_fscan1(const int* fastflag, const u8* flags, u8* prefix,
                         int* bsums, int n) {
    if (*fastflag) return;
    __shared__ int sh[256];
    int t = threadIdx.x;
    int i = blockIdx.x * 256 + t;
    int v = (i < n) ? (int)flags[i] : 0;
    sh[t] = v;
    __syncthreads();
    for (int off = 1; off < 256; off <<= 1) {
        int xv = (t >= off) ? sh[t - off] : 0;
        __syncthreads();
        sh[t] += xv;
        __syncthreads();
    }
    if (i < n) prefix[i] = (u8)(sh[t] - v);
    if (t == 255) bsums[blockIdx.x] = sh[255];
}

__global__ void k_fscan2(const int* fastflag, const int* bsums, int nb,
                         int* bpre, int* total, float* out) {
    if (*fastflag) return;
    __shared__ int sh[256];
    int t = threadIdx.x;
    int C = (nb + 255) / 256;
    int lo = t * C;
    int hi = lo + C < nb ? lo + C : nb;
    int s = 0;
    for (int i = lo; i < hi; i++) s += bsums[i];
    sh[t] = s;
    __syncthreads();
    for (int off = 1; off < 256; off <<= 1) {
        int xv = (t >= off) ? sh[t - off] : 0;
        __syncthreads();
        sh[t] += xv;
        __syncthreads();
    }
    int run = sh[t] - s;
    for (int i = lo; i < hi; i++) { bpre[i] = run; run += bsums[i]; }
    if (t == 255) {
        int T = sh[255];
        *total = T;
        if (T > MAXV) T = MAXV;
        out[OUT_VNUM] = bfround((float)T);
    }
}

__global__ void k_fassign(const int* fastflag, const int* keys, int N,
                          const u8* flags, const u8* prefix, const int* bpre,
                          const u64* ftab, const u64* extras, const u32* bcount,
                          const u64* ovf, const u32* ocount, int nb,
                          u64* firsts, int* cnt, int* lists) {
    if (*fastflag) return;
    int b = blockIdx.x;
    int t = threadIdx.x;
    u64 rec;
    if (b < nb) {
        int i = b * 256 + t;
        int vbase = bpre[b];
        if (vbase < MAXV && i < N && flags[i]) {
            int v = (int)prefix[i] + vbase;
            if (v < MAXV)
                firsts[v] = ((u64)(u32)keys[i] << 32) | (u32)i;
        }
        u32 c = bcount[b];
        if (c > SEGC) c = SEGC;
        if ((u32)t >= c) return;
        rec = extras[(size_t)b * SEGC + t];
    } else {
        u32 j = (u32)(b - nb) * 256 + t;
        u32 oc = *ocount;
        if (oc > OCAP) oc = OCAP;
        if (j >= oc) return;
        rec = ovf[j];
    }
    u32 slot = (u32)(rec >> 32);
    u32 pidx = (u32)rec;
    u32 f = (u32)ftab[slot];            // LE low word = min idx
    int v = (int)prefix[f] + bpre[f >> 8];
    if (v >= MAXV) return;
    int pos = atomicAdd(&cnt[v], 1);
    if (pos < LCAP) lists[v * LCAP + pos] = (int)pidx;
}

// Sole output writer (d_out is poisoned each call): per v writes the full
// 10x5 voxel block, coors (coalesced in v), npv.
__global__ void k_write(const void* pts, const int* dflag, const u64* firsts,
                        const int* cnt, const int* lists, const int* total,
                        float* out) {
    int v = blockIdx.x * blockDim.x + threadIdx.x;
    if (v >= MAXV) return;
    int T = *total;
    if (T > MAXV) T = MAXV;
    float* dst = out + (size_t)v * MAXP * 5;
    if (v >= T) {
        for (int j = 0; j < MAXP * 5; j++) dst[j] = 0.0f;
        out[OUT_COORS + v * 3 + 0] = -1.0f;
        out[OUT_COORS + v * 3 + 1] = -1.0f;
        out[OUT_COORS + v * 3 + 2] = -1.0f;
        out[OUT_NPV + v] = 0.0f;
        return;
    }
    u64 fe = firsts[v];
    u32 key = (u32)(fe >> 32);
    int f = (int)(u32)fe;
    int cx = (int)(key % GXC);
    u32 r = key / GXC;
    int cy = (int)(r % GYC);
    int cz = (int)(r / GYC);
    out[OUT_COORS + v * 3 + 0] = bfround((float)cz);
    out[OUT_COORS + v * 3 + 1] = bfround((float)cy);
    out[OUT_COORS + v * 3 + 2] = bfround((float)cx);
    int c = cnt[v];
    int np = 1 + c;
    if (np > MAXP) np = MAXP;
    out[OUT_NPV + v] = (float)np;
    int bf = *dflag;
    for (int j = 0; j < 5; j++) dst[j] = bfround(load_ch(pts, f, j, bf));
    if (c > 0) {
        int m = (c < LCAP) ? c : LCAP;
        int idx[LCAP];
        for (int j = 0; j < m; j++) idx[j] = lists[v * LCAP + j];
        for (int a = 1; a < m; a++) {  // sort dup indices -> insertion order
            int kk = idx[a];
            int b2 = a - 1;
            while (b2 >= 0 && idx[b2] > kk) { idx[b2 + 1] = idx[b2]; b2--; }
            idx[b2 + 1] = kk;
        }
        for (int rr = 1; rr < np; rr++) {
            int p = idx[rr - 1];
            for (int j = 0; j < 5; j++)
                dst[rr * 5 + j] = bfround(load_ch(pts, p, j, bf));
        }
    }
    for (int rr = np; rr < MAXP; rr++)
        for (int j = 0; j < 5; j++) dst[rr * 5 + j] = 0.0f;
}

extern "C" void kernel_launch(void* const* d_in, const int* in_sizes, int n_in,
                              void* d_out, int out_size, void* d_ws, size_t ws_size,
                              hipStream_t stream) {
    (void)n_in; (void)out_size;
    const void* pts = d_in[0];
    int N = in_sizes[0] / 5;
    float* out = (float*)d_out;
    if (N <= 0 || N > 16384 * 256) return;

    int Peff = N < PPREF ? N : PPREF;
    int nbp = (Peff + 255) / 256;
    int nb = (N + 255) / 256;
    size_t npad = ((size_t)N + 255) & ~(size_t)255;

    // ws: keys[npad]*4 | flags[npad] | prefix[npad] | bsums/bpre[16384]*4 |
    //     scalars | tkey/tidx[HCAP]*4 | firsts[MAXV]*8 | cnt[MAXV]*4 |
    //     lists[MAXV*LCAP]*4 | extras[nb*SEGC]*8 | bcount[nb]*4 |
    //     ovf[OCAP]*8 | ftab[FHCAP]*8            (~43.5 MB at N=2M)
    size_t need = npad * 4 + npad + npad + 16384 * 8 + 512
                + (size_t)HCAP * 8
                + (size_t)MAXV * 8 + (size_t)MAXV * 4 + (size_t)MAXV * LCAP * 4
                + (size_t)nb * SEGC * 8 + (((size_t)nb * 4 + 255) & ~(size_t)255)
                + (size_t)OCAP * 8 + (size_t)FHCAP * 8;
    if (ws_size < need) return;

    char* w = (char*)d_ws;
    int* keys   = (int*)w;  w += npad * 4;
    u8*  flags  = (u8*)w;   w += npad;
    u8*  prefix = (u8*)w;   w += npad;
    int* bsums  = (int*)w;  w += 16384 * 4;
    int* bpre   = (int*)w;  w += 16384 * 4;
    int* total  = (int*)w;  w += 128;
    int* dflag  = (int*)w;  w += 128;
    u32* ocount = (u32*)w;  w += 128;
    int* fastflag = (int*)w; w += 128;
    u32* tkey   = (u32*)w;  w += (size_t)HCAP * 4;
    u32* tidx   = (u32*)w;  w += (size_t)HCAP * 4;
    u64* firsts = (u64*)w;  w += (size_t)MAXV * 8;
    int* cnt    = (int*)w;  w += (size_t)MAXV * 4;
    int* lists  = (int*)w;  w += (size_t)MAXV * LCAP * 4;
    u64* extras = (u64*)w;  w += (size_t)nb * SEGC * 8;
    u32* bcount = (u32*)w;  w += ((size_t)nb * 4 + 255) & ~(size_t)255;
    u64* ovf    = (u64*)w;  w += (size_t)OCAP * 8;
    u64* ftab   = (u64*)w;

    k_init<<<2048, 256, 0, stream>>>(tkey, tidx, cnt, N, (const u16*)pts,
                                     dflag, ocount, total, fastflag);
    Voxelization_87136296501765_kernel<<<nb, 256, 0, stream>>>(
        pts, N, dflag, keys, flags);
    k_insert<<<nbp, 256, 0, stream>>>(keys, Peff, tkey, tidx, flags,
                                      extras, bcount, ovf, ocount);
    k_scan1<<<nbp, 256, 0, stream>>>(flags, prefix, bsums, Peff);
    k_scan2p<<<1, 256, 0, stream>>>(bsums, nbp, bpre, total, fastflag, out);
    k_assign_pre<<<nbp + OCAP / 256, 256, 0, stream>>>(
        keys, Peff, flags, prefix, bpre, tidx, extras, bcount, ovf, ocount,
        nbp, firsts, cnt, lists);
    if (N > Peff) {
        int nbs = (N - Peff + 255) / 256;
        k_lookup<<<nbs, 256, 0, stream>>>(keys, N, Peff, fastflag, tkey, tidx,
                                          prefix, bpre, cnt, lists);
        // gated fallback (runs only if distinct(prefix) < MAXV)
        k_finit<<<2048, 256, 0, stream>>>(fastflag, ftab, cnt, ocount);
        k_finsert<<<nb, 256, 0, stream>>>(fastflag, keys, N, ftab, flags,
                                          extras, bcount, ovf, ocount);
        k_fscan1<<<nb, 256, 0, stream>>>(fastflag, flags, prefix, bsums, N);
        k_fscan2<<<1, 256, 0, stream>>>(fastflag, bsums, nb, bpre, total, out);
        k_fassign<<<nb + OCAP / 256, 256, 0, stream>>>(
            fastflag, keys, N, flags, prefix, bpre, ftab, extras, bcount,
            ovf, ocount, nb, firsts, cnt, lists);
    }
    k_write<<<(MAXV + 255) / 256, 256, 0, stream>>>(pts, dflag, firsts, cnt,
                                                    lists, total, out);
}

// Round 4
// 197.117 us; speedup vs baseline: 3.1657x; 1.0330x over previous
//

#include <hip/hip_runtime.h>
#include <hip/hip_bf16.h>

// Deterministic hard_voxelize. Round 19: prefix/suffix structure from R18
// (203us), with three reductions:
//  - packed u64 prefix table (key<<32|minidx), R15's verified CAS+atomicMin
//    emission: 1 scattered 64B RMW line/point instead of 2 (tkey+tidx).
//  - keys[] array deleted: canonical pass = prefix validity flags only
//    (262K pts); suffix lookup + assign recompute keys from pts (VALU-cheap,
//    coalesced pts reads). Removes the only remaining full-N staging pass.
//  - assign+lookup fused into one kernel (block-range roles).
// Flag-clear stays race-free: validity flags are written by the PRIOR
// dispatch (canonical / gated finit), insert kernels only clear dup bytes ->
// single writer per byte per dispatch (the R18 safety argument).
// Measured laws: scattered 64B RMW ~1.45TB/s (64B/pt packed); returning-
// atomic+scatter chains ~0.5TB/s (R17); single-CU serial scans are
// transaction-bound (R16); harness poison fill (~42us @6.3TB/s) not ours.

#define MAXV 150000
#define MAXP 10
#define LCAP 12
#define GXC 1504
#define GYC 1504
#define GZC 40

#define PPREF 262144           // prefix length (1024 blocks)
#define HC 19
#define HCAP (1u << HC)        // 524288 slots; load <= 0.5 at P=256K
#define HMASK (HCAP - 1u)
#define FHCAP (1u << 21)       // fallback packed table (16.8MB), gated only
#define FHMASK (FHCAP - 1u)
#define SEGC 16                // extras segment per block
#define OCAP (1 << 15)         // global overflow (adversarial only)

#define OUT_COORS 7500000
#define OUT_NPV   7950000
#define OUT_VNUM  8100000
#define EMPTY64 0xFFFFFFFFFFFFFFFFULL

typedef unsigned char u8;
typedef unsigned short u16;
typedef unsigned int u32;
typedef unsigned long long u64;

__device__ __forceinline__ u16 f2bf(float v) {  // round-to-nearest-even
    u32 b = __float_as_uint(v);
    return (u16)((b + 0x7FFFu + ((b >> 16) & 1u)) >> 16);
}
__device__ __forceinline__ float bf2f(u16 u) {
    return __uint_as_float(((u32)u) << 16);
}
__device__ __forceinline__ float bfround(float v) { return bf2f(f2bf(v)); }

__device__ __forceinline__ u32 hslot(int key) {
    return (((u32)key * 2654435761u) >> 12) & HMASK;
}
__device__ __forceinline__ u32 fhslot(int key) {
    return (((u32)key * 2654435761u) >> 10) & FHMASK;
}

// Init (+ fused dtype detect in block 0): tab=EMPTY, cnt=0, scalars.
__global__ void k_init(u64* tab, int* cnt, int N, const u16* raw,
                       int* dflag, u32* ocount, int* total, int* fastflag) {
    if (blockIdx.x == 0) {
        __shared__ int v32;
        __shared__ int v16;
        if (threadIdx.x == 0) { v32 = 0; v16 = 0; }
        __syncthreads();
        int r = (int)threadIdx.x * 37;
        if (r >= N) r = N > 0 ? N - 1 : 0;
        const float* p32 = (const float*)raw;
        float a3 = p32[r * 5 + 3];
        float a4 = p32[r * 5 + 4];
        float b3 = bf2f(raw[r * 5 + 3]);
        float b4 = bf2f(raw[r * 5 + 4]);
        int ok32 = (a3 == a3) && (a4 == a4) &&
                   (a3 >= -0.001f) && (a3 <= 1.001f) && (a4 >= -0.001f) && (a4 <= 1.001f);
        int okbf = (b3 == b3) && (b4 == b4) &&
                   (b3 >= -0.001f) && (b3 <= 1.001f) && (b4 >= -0.001f) && (b4 <= 1.001f);
        if (ok32) atomicAdd(&v32, 1);
        if (okbf) atomicAdd(&v16, 1);
        __syncthreads();
        if (threadIdx.x == 0) *dflag = (v16 > v32) ? 1 : 0;
    }
    int stride = gridDim.x * blockDim.x;
    int i0 = blockIdx.x * blockDim.x + threadIdx.x;
    for (u32 i = (u32)i0; i < HCAP; i += (u32)stride) tab[i] = EMPTY64;
    for (int i = i0; i < MAXV; i += stride) cnt[i] = 0;
    if (i0 == 0) { *ocount = 0u; *total = 0; *fastflag = 0; }
}

__device__ __forceinline__ float load_ch(const void* pts, int i, int j, int bf) {
    if (bf) return bf2f(((const u16*)pts)[i * 5 + j]);
    return ((const float*)pts)[i * 5 + j];
}

// Exact f32 sub+div+floor, matching reference arithmetic. -1 if out of range.
__device__ __forceinline__ int point_key(const void* pts, int i, int bf) {
    float x = load_ch(pts, i, 0, bf);
    float y = load_ch(pts, i, 1, bf);
    float z = load_ch(pts, i, 2, bf);
    int cx = (int)floorf((x - (-75.2f)) / 0.1f);
    int cy = (int)floorf((y - (-75.2f)) / 0.1f);
    int cz = (int)floorf((z - (-2.0f)) / 0.15f);
    if (cx < 0 || cx >= GXC || cy < 0 || cy >= GYC || cz < 0 || cz >= GZC) return -1;
    return (cz * GYC + cy) * GXC + cx;
}

// Canonical kernel: prefix validity flags (written BEFORE insert so insert's
// inline dup-clear has a single writer per byte per dispatch).
__global__ void Voxelization_87136296501765_kernel(
        const void* pts, int Peff, const int* dflag, u8* flags) {
    int i = blockIdx.x * 256 + threadIdx.x;
    if (i >= Peff) return;
    flags[i] = (u8)(point_key(pts, i, *dflag) >= 0);
}

// Prefix hash insert, packed u64 (key<<32|idx): CAS-claim, atomicMin on dups.
// Emission rule (R15-verified): prev low pm > i -> atomicMin, displaced old
// (or self) is the extra; pm <= i -> self is extra. Exactly-once per non-min
// point; clears its flag inline (validity written in prior dispatch).
__global__ void k_insert(const void* pts, int Peff, const int* dflag,
                         u64* tab, u8* flags, u64* extras, u32* bcount,
                         u64* ovf, u32* ocount) {
    __shared__ u32 s_cnt;
    if (threadIdx.x == 0) s_cnt = 0;
    __syncthreads();
    int i = blockIdx.x * 256 + threadIdx.x;
    bool has = false;
    u32 eslot = 0, eidx = 0;
    if (i < Peff) {
        int key = point_key(pts, i, *dflag);
        if (key >= 0) {
            u64 mine = ((u64)(u32)key << 32) | (u32)i;
            u32 slot = hslot(key);
            for (;;) {
                u64 prev = atomicCAS(&tab[slot], EMPTY64, mine);
                if (prev == EMPTY64) break;           // first writer
                if ((u32)(prev >> 32) == (u32)key) {  // same voxel -> dup
                    u32 pm = (u32)prev;
                    if (pm > (u32)i) {
                        u64 old = atomicMin(&tab[slot], mine);
                        u32 om = (u32)old;
                        eidx = (om > (u32)i) ? om : (u32)i;
                    } else {
                        eidx = (u32)i;
                    }
                    eslot = slot;
                    has = true;
                    flags[eidx] = 0;
                    break;
                }
                slot = (slot + 1u) & HMASK;
            }
        }
    }
    if (has) {
        u32 pos = atomicAdd(&s_cnt, 1u);
        u64 rec = ((u64)eslot << 32) | eidx;
        if (pos < SEGC) {
            extras[(size_t)blockIdx.x * SEGC + pos] = rec;
        } else {
            u32 op = atomicAdd(ocount, 1u);
            if (op < OCAP) ovf[op] = rec;
        }
    }
    __syncthreads();
    if (threadIdx.x == 0) bcount[blockIdx.x] = s_cnt;
}

// flags -> per-block exclusive rank + block sums.
__global__ void k_scan1(const u8* flags, u8* prefix, int* bsums, int n) {
    __shared__ int sh[256];
    int t = threadIdx.x;
    int i = blockIdx.x * 256 + t;
    int v = (i < n) ? (int)flags[i] : 0;
    sh[t] = v;
    __syncthreads();
    for (int off = 1; off < 256; off <<= 1) {
        int xv = (t >= off) ? sh[t - off] : 0;
        __syncthreads();
        sh[t] += xv;
        __syncthreads();
    }
    if (i < n) prefix[i] = (u8)(sh[t] - v);
    if (t == 255) bsums[blockIdx.x] = sh[255];
}

// Single-block scan of nbp (<=1024) block sums. Writes total, fastflag, vnum.
__global__ void k_scan2p(const int* bsums, int nbp, int* bpre,
                         int* total, int* fastflag, float* out) {
    __shared__ int sh[256];
    int t = threadIdx.x;
    int C = (nbp + 255) / 256;
    int lo = t * C;
    int hi = lo + C < nbp ? lo + C : nbp;
    int s = 0;
    for (int i = lo; i < hi; i++) s += bsums[i];
    sh[t] = s;
    __syncthreads();
    for (int off = 1; off < 256; off <<= 1) {
        int xv = (t >= off) ? sh[t - off] : 0;
        __syncthreads();
        sh[t] += xv;
        __syncthreads();
    }
    int run = sh[t] - s;
    for (int i = lo; i < hi; i++) { bpre[i] = run; run += bsums[i]; }
    if (t == 255) {
        int T = sh[255];
        *total = T;
        *fastflag = (T >= MAXV) ? 1 : 0;
        if (T > MAXV) T = MAXV;
        out[OUT_VNUM] = bfround((float)T);
    }
}

// Fused assign + suffix lookup.
// Blocks [0,nbp): prefix assign (firsts from recomputed key) + extras tail.
// Blocks [nbp,nbp+nbs): fast-path suffix probes (key recomputed from pts,
//   read-only table probes; hit -> append to voxel's list).
// Blocks beyond: overflow records.
__global__ void k_assign_lookup(const void* pts, int N, int Peff,
                                const int* dflag, const int* fastflag,
                                const u8* flags, const u8* prefix,
                                const int* bpre, const u64* tab,
                                const u64* extras, const u32* bcount,
                                const u64* ovf, const u32* ocount,
                                int nbp, int nbs,
                                u64* firsts, int* cnt, int* lists) {
    int b = blockIdx.x;
    int t = threadIdx.x;
    u64 rec;
    if (b < nbp) {
        int i = b * 256 + t;
        int vbase = bpre[b];
        if (vbase < MAXV && i < Peff && flags[i]) {
            int v = (int)prefix[i] + vbase;
            if (v < MAXV) {
                int key = point_key(pts, i, *dflag);  // valid by construction
                firsts[v] = ((u64)(u32)key << 32) | (u32)i;
            }
        }
        u32 c = bcount[b];
        if (c > SEGC) c = SEGC;
        if ((u32)t >= c) return;
        rec = extras[(size_t)b * SEGC + t];
    } else if (b < nbp + nbs) {
        if (*fastflag == 0) return;
        int i = Peff + (b - nbp) * 256 + t;
        if (i >= N) return;
        int key = point_key(pts, i, *dflag);
        if (key < 0) return;
        u32 slot = hslot(key);
        for (;;) {
            u64 e = tab[slot];
            if (e == EMPTY64) return;       // voxel not opened in prefix
            if ((u32)(e >> 32) == (u32)key) {
                u32 f = (u32)e;
                int v = (int)prefix[f] + bpre[f >> 8];
                if (v < MAXV) {
                    int pos = atomicAdd(&cnt[v], 1);
                    if (pos < LCAP) lists[v * LCAP + pos] = i;
                }
                return;
            }
            slot = (slot + 1u) & HMASK;
        }
    } else {
        u32 j = (u32)(b - nbp - nbs) * 256 + t;
        u32 oc = *ocount;
        if (oc > OCAP) oc = OCAP;
        if (j >= oc) return;
        rec = ovf[j];
    }
    u32 slot = (u32)(rec >> 32);
    u32 pidx = (u32)rec;
    u32 f = (u32)tab[slot];                 // LE low word = min idx
    int v = (int)prefix[f] + bpre[f >> 8];
    if (v >= MAXV) return;
    int pos = atomicAdd(&cnt[v], 1);
    if (pos < LCAP) lists[v * LCAP + pos] = (int)pidx;
}

// ---- Fallback path (distinct(prefix) < MAXV; gated, never on bench) ----

// ftab=EMPTY, cnt=0, ocount=0, and validity flags for ALL N (recomputed) so
// finsert's inline dup-clear is single-writer-per-byte.
__global__ void k_finit(const int* fastflag, const void* pts, int N,
                        const int* dflag, u64* ftab, int* cnt, u32* ocount,
                        u8* flags) {
    if (*fastflag) return;
    int stride = gridDim.x * blockDim.x;
    int i0 = blockIdx.x * blockDim.x + threadIdx.x;
    for (u32 i = (u32)i0; i < FHCAP; i += (u32)stride) ftab[i] = EMPTY64;
    for (int i = i0; i < MAXV; i += stride) cnt[i] = 0;
    int bf = *dflag;
    for (int i = i0; i < N; i += stride)
        flags[i] = (u8)(point_key(pts, i, bf) >= 0);
    if (i0 == 0) *ocount = 0u;
}

__global__ void k_finsert(const int* fastflag, const void* pts, int N,
                          const int* dflag, u64* ftab, u8* flags,
                          u64* extras, u32* bcount, u64* ovf, u32* ocount) {
    if (*fastflag) return;
    __shared__ u32 s_cnt;
    if (threadIdx.x == 0) s_cnt = 0;
    __syncthreads();
    int i = blockIdx.x * 256 + threadIdx.x;
    bool has = false;
    u32 eslot = 0, eidx = 0;
    if (i < N) {
        int key = point_key(pts, i, *dflag);
        if (key >= 0) {
            u64 mine = ((u64)(u32)key << 32) | (u32)i;
            u32 slot = fhslot(key);
            for (;;) {
                u64 prev = atomicCAS(&ftab[slot], EMPTY64, mine);
                if (prev == EMPTY64) break;
                if ((u32)(prev >> 32) == (u32)key) {
                    u32 pm = (u32)prev;
                    if (pm > (u32)i) {
                        u64 old = atomicMin(&ftab[slot], mine);
                        u32 om = (u32)old;
                        eidx = (om > (u32)i) ? om : (u32)i;
                    } else {
                        eidx = (u32)i;
                    }
                    eslot = slot;
                    has = true;
                    flags[eidx] = 0;
                    break;
                }
                slot = (slot + 1u) & FHMASK;
            }
        }
    }
    if (has) {
        u32 pos = atomicAdd(&s_cnt, 1u);
        u64 rec = ((u64)eslot << 32) | eidx;
        if (pos < SEGC) {
            extras[(size_t)blockIdx.x * SEGC + pos] = rec;
        } else {
            u32 op = atomicAdd(ocount, 1u);
            if (op < OCAP) ovf[op] = rec;
        }
    }
    __syncthreads();
    if (threadIdx.x == 0) bcount[blockIdx.x] = s_cnt;
}

__global__ void k_fscan1(const int* fastflag, const u8* flags, u8* prefix,
                         int* bsums, int n) {
    if (*fastflag) return;
    __shared__ int sh[256];
    int t = threadIdx.x;
    int i = blockIdx.x * 256 + t;
    int v = (i < n) ? (int)flags[i] : 0;
    sh[t] = v;
    __syncthreads();
    for (int off = 1; off < 256; off <<= 1) {
        int xv = (t >= off) ? sh[t - off] : 0;
        __syncthreads();
        sh[t] += xv;
        __syncthreads();
    }
    if (i < n) prefix[i] = (u8)(sh[t] - v);
    if (t == 255) bsums[blockIdx.x] = sh[255];
}

__global__ void k_fscan2(const int* fastflag, const int* bsums, int nb,
                         int* bpre, int* total, float* out) {
    if (*fastflag) return;
    __shared__ int sh[256];
    int t = threadIdx.x;
    int C = (nb + 255) / 256;
    int lo = t * C;
    int hi = lo + C < nb ? lo + C : nb;
    int s = 0;
    for (int i = lo; i < hi; i++) s += bsums[i];
    sh[t] = s;
    __syncthreads();
    for (int off = 1; off < 256; off <<= 1) {
        int xv = (t >= off) ? sh[t - off] : 0;
        __syncthreads();
        sh[t] += xv;
        __syncthreads();
    }
    int run = sh[t] - s;
    for (int i = lo; i < hi; i++) { bpre[i] = run; run += bsums[i]; }
    if (t == 255) {
        int T = sh[255];
        *total = T;
        if (T > MAXV) T = MAXV;
        out[OUT_VNUM] = bfround((float)T);
    }
}

__global__ void k_fassign(const int* fastflag, const void* pts, int N,
                          const int* dflag, const u8* flags, const u8* prefix,
                          const int* bpre, const u64* ftab, const u64* extras,
                          const u32* bcount, const u64* ovf, const u32* ocount,
                          int nb, u64* firsts, int* cnt, int* lists) {
    if (*fastflag) return;
    int b = blockIdx.x;
    int t = threadIdx.x;
    u64 rec;
    if (b < nb) {
        int i = b * 256 + t;
        int vbase = bpre[b];
        if (vbase < MAXV && i < N && flags[i]) {
            int v = (int)prefix[i] + vbase;
            if (v < MAXV) {
                int key = point_key(pts, i, *dflag);
                firsts[v] = ((u64)(u32)key << 32) | (u32)i;
            }
        }
        u32 c = bcount[b];
        if (c > SEGC) c = SEGC;
        if ((u32)t >= c) return;
        rec = extras[(size_t)b * SEGC + t];
    } else {
        u32 j = (u32)(b - nb) * 256 + t;
        u32 oc = *ocount;
        if (oc > OCAP) oc = OCAP;
        if (j >= oc) return;
        rec = ovf[j];
    }
    u32 slot = (u32)(rec >> 32);
    u32 pidx = (u32)rec;
    u32 f = (u32)ftab[slot];
    int v = (int)prefix[f] + bpre[f >> 8];
    if (v >= MAXV) return;
    int pos = atomicAdd(&cnt[v], 1);
    if (pos < LCAP) lists[v * LCAP + pos] = (int)pidx;
}

// Sole output writer (d_out is poisoned each call): per v writes the full
// 10x5 voxel block, coors (coalesced in v), npv.
__global__ void k_write(const void* pts, const int* dflag, const u64* firsts,
                        const int* cnt, const int* lists, const int* total,
                        float* out) {
    int v = blockIdx.x * blockDim.x + threadIdx.x;
    if (v >= MAXV) return;
    int T = *total;
    if (T > MAXV) T = MAXV;
    float* dst = out + (size_t)v * MAXP * 5;
    if (v >= T) {
        for (int j = 0; j < MAXP * 5; j++) dst[j] = 0.0f;
        out[OUT_COORS + v * 3 + 0] = -1.0f;
        out[OUT_COORS + v * 3 + 1] = -1.0f;
        out[OUT_COORS + v * 3 + 2] = -1.0f;
        out[OUT_NPV + v] = 0.0f;
        return;
    }
    u64 fe = firsts[v];
    u32 key = (u32)(fe >> 32);
    int f = (int)(u32)fe;
    int cx = (int)(key % GXC);
    u32 r = key / GXC;
    int cy = (int)(r % GYC);
    int cz = (int)(r / GYC);
    out[OUT_COORS + v * 3 + 0] = bfround((float)cz);
    out[OUT_COORS + v * 3 + 1] = bfround((float)cy);
    out[OUT_COORS + v * 3 + 2] = bfround((float)cx);
    int c = cnt[v];
    int np = 1 + c;
    if (np > MAXP) np = MAXP;
    out[OUT_NPV + v] = (float)np;
    int bf = *dflag;
    for (int j = 0; j < 5; j++) dst[j] = bfround(load_ch(pts, f, j, bf));
    if (c > 0) {
        int m = (c < LCAP) ? c : LCAP;
        int idx[LCAP];
        for (int j = 0; j < m; j++) idx[j] = lists[v * LCAP + j];
        for (int a = 1; a < m; a++) {  // sort dup indices -> insertion order
            int kk = idx[a];
            int b2 = a - 1;
            while (b2 >= 0 && idx[b2] > kk) { idx[b2 + 1] = idx[b2]; b2--; }
            idx[b2 + 1] = kk;
        }
        for (int rr = 1; rr < np; rr++) {
            int p = idx[rr - 1];
            for (int j = 0; j < 5; j++)
                dst[rr * 5 + j] = bfround(load_ch(pts, p, j, bf));
        }
    }
    for (int rr = np; rr < MAXP; rr++)
        for (int j = 0; j < 5; j++) dst[rr * 5 + j] = 0.0f;
}

extern "C" void kernel_launch(void* const* d_in, const int* in_sizes, int n_in,
                              void* d_out, int out_size, void* d_ws, size_t ws_size,
                              hipStream_t stream) {
    (void)n_in; (void)out_size;
    const void* pts = d_in[0];
    int N = in_sizes[0] / 5;
    float* out = (float*)d_out;
    if (N <= 0 || N > 16384 * 256) return;

    int Peff = N < PPREF ? N : PPREF;
    int nbp = (Peff + 255) / 256;
    int nbs = (N > Peff) ? (N - Peff + 255) / 256 : 0;
    int nb = (N + 255) / 256;
    size_t npad = ((size_t)N + 255) & ~(size_t)255;

    // ws: flags[npad] | prefix[npad] | bsums/bpre[16384]*4 | scalars |
    //     tab[HCAP]*8 | firsts[MAXV]*8 | cnt[MAXV]*4 | lists[MAXV*LCAP]*4 |
    //     extras[nb*SEGC]*8 | bcount[nb]*4 | ovf[OCAP]*8 | ftab[FHCAP]*8
    //     (~35 MB at N=2M)
    size_t need = npad + npad + 16384 * 8 + 512
                + (size_t)HCAP * 8
                + (size_t)MAXV * 8 + (size_t)MAXV * 4 + (size_t)MAXV * LCAP * 4
                + (size_t)nb * SEGC * 8 + (((size_t)nb * 4 + 255) & ~(size_t)255)
                + (size_t)OCAP * 8 + (size_t)FHCAP * 8;
    if (ws_size < need) return;

    char* w = (char*)d_ws;
    u8*  flags  = (u8*)w;   w += npad;
    u8*  prefix = (u8*)w;   w += npad;
    int* bsums  = (int*)w;  w += 16384 * 4;
    int* bpre   = (int*)w;  w += 16384 * 4;
    int* total  = (int*)w;  w += 128;
    int* dflag  = (int*)w;  w += 128;
    u32* ocount = (u32*)w;  w += 128;
    int* fastflag = (int*)w; w += 128;
    u64* tab    = (u64*)w;  w += (size_t)HCAP * 8;
    u64* firsts = (u64*)w;  w += (size_t)MAXV * 8;
    int* cnt    = (int*)w;  w += (size_t)MAXV * 4;
    int* lists  = (int*)w;  w += (size_t)MAXV * LCAP * 4;
    u64* extras = (u64*)w;  w += (size_t)nb * SEGC * 8;
    u32* bcount = (u32*)w;  w += ((size_t)nb * 4 + 255) & ~(size_t)255;
    u64* ovf    = (u64*)w;  w += (size_t)OCAP * 8;
    u64* ftab   = (u64*)w;

    k_init<<<2048, 256, 0, stream>>>(tab, cnt, N, (const u16*)pts,
                                     dflag, ocount, total, fastflag);
    Voxelization_87136296501765_kernel<<<nbp, 256, 0, stream>>>(
        pts, Peff, dflag, flags);
    k_insert<<<nbp, 256, 0, stream>>>(pts, Peff, dflag, tab, flags,
                                      extras, bcount, ovf, ocount);
    k_scan1<<<nbp, 256, 0, stream>>>(flags, prefix, bsums, Peff);
    k_scan2p<<<1, 256, 0, stream>>>(bsums, nbp, bpre, total, fastflag, out);
    k_assign_lookup<<<nbp + nbs + OCAP / 256, 256, 0, stream>>>(
        pts, N, Peff, dflag, fastflag, flags, prefix, bpre, tab,
        extras, bcount, ovf, ocount, nbp, nbs, firsts, cnt, lists);
    if (N > Peff) {
        // gated fallback (runs only if distinct(prefix) < MAXV)
        k_finit<<<2048, 256, 0, stream>>>(fastflag, pts, N, dflag, ftab, cnt,
                                          ocount, flags);
        k_finsert<<<nb, 256, 0, stream>>>(fastflag, pts, N, dflag, ftab,
                                          flags, extras, bcount, ovf, ocount);
        k_fscan1<<<nb, 256, 0, stream>>>(fastflag, flags, prefix, bsums, N);
        k_fscan2<<<1, 256, 0, stream>>>(fastflag, bsums, nb, bpre, total, out);
        k_fassign<<<nb + OCAP / 256, 256, 0, stream>>>(
            fastflag, pts, N, dflag, flags, prefix, bpre, ftab, extras,
            bcount, ovf, ocount, nb, firsts, cnt, lists);
    }
    k_write<<<(MAXV + 255) / 256, 256, 0, stream>>>(pts, dflag, firsts, cnt,
                                                    lists, total, out);
}

// Round 5
// 188.829 us; speedup vs baseline: 3.3046x; 1.0439x over previous
//

#include <hip/hip_runtime.h>
#include <hip/hip_bf16.h>

// Deterministic hard_voxelize. Round 20: R19 structure (197us) with:
//  - u16 tag filter (1MB, L2-resident) beside the 4MB packed table: suffix
//    membership test reads 2B tags; tab (64B lines) touched only on tag match
//    (~0.65% hits + 2^-16 false positives). Cuts the probe-path line fetches.
//  - canonical+insert fused (one prefix pts pass). Dup flag-clears deferred
//    to k_clear over extras/ovf records (single-writer-per-byte preserved).
//  - suffix: 2 points/thread -> 2 independent pts-load chains in flight.
//  - fallback: tries-bounded probes + ws-sized table (2^22 if fits else 2^21)
//    -> no unbounded loop on adversarial >2M-distinct inputs.
// Measured laws: scattered 64B RMW ~1.45TB/s (64B/pt packed); returning-
// atomic+scatter chains ~0.5TB/s (R17); single-CU serial scans transaction-
// bound (R16); suffix probe kernel is latency-profile, not BW (R19: 1.26TB/s,
// VALU 13.5%); harness poison fill (~44us @6.3TB/s) not ours.

#define MAXV 150000
#define MAXP 10
#define LCAP 12
#define GXC 1504
#define GYC 1504
#define GZC 40

#define PPREF 262144           // prefix length (1024 blocks)
#define HC 19
#define HCAP (1u << HC)        // 524288 slots; load <= 0.5 at P=256K
#define HMASK (HCAP - 1u)
#define SEGC 16                // extras segment per block
#define OCAP (1 << 15)         // global overflow (adversarial only)

#define OUT_COORS 7500000
#define OUT_NPV   7950000
#define OUT_VNUM  8100000
#define EMPTY64 0xFFFFFFFFFFFFFFFFULL

typedef unsigned char u8;
typedef unsigned short u16;
typedef unsigned int u32;
typedef unsigned long long u64;

__device__ __forceinline__ u16 f2bf(float v) {  // round-to-nearest-even
    u32 b = __float_as_uint(v);
    return (u16)((b + 0x7FFFu + ((b >> 16) & 1u)) >> 16);
}
__device__ __forceinline__ float bf2f(u16 u) {
    return __uint_as_float(((u32)u) << 16);
}
__device__ __forceinline__ float bfround(float v) { return bf2f(f2bf(v)); }

__device__ __forceinline__ u32 hslot(int key) {
    return (((u32)key * 2654435761u) >> 12) & HMASK;
}
__device__ __forceinline__ u16 htag(int key) {  // independent 2nd hash, !=0
    return (u16)((((u32)key) * 0x85EBCA6Bu) >> 16) | (u16)1;
}

// Init (+ fused dtype detect in block 0): tab=EMPTY, tag=0, cnt=0, scalars.
__global__ void k_init(u64* tab, u16* tag, int* cnt, int N, const u16* raw,
                       int* dflag, u32* ocount, int* total, int* fastflag) {
    if (blockIdx.x == 0) {
        __shared__ int v32;
        __shared__ int v16;
        if (threadIdx.x == 0) { v32 = 0; v16 = 0; }
        __syncthreads();
        int r = (int)threadIdx.x * 37;
        if (r >= N) r = N > 0 ? N - 1 : 0;
        const float* p32 = (const float*)raw;
        float a3 = p32[r * 5 + 3];
        float a4 = p32[r * 5 + 4];
        float b3 = bf2f(raw[r * 5 + 3]);
        float b4 = bf2f(raw[r * 5 + 4]);
        int ok32 = (a3 == a3) && (a4 == a4) &&
                   (a3 >= -0.001f) && (a3 <= 1.001f) && (a4 >= -0.001f) && (a4 <= 1.001f);
        int okbf = (b3 == b3) && (b4 == b4) &&
                   (b3 >= -0.001f) && (b3 <= 1.001f) && (b4 >= -0.001f) && (b4 <= 1.001f);
        if (ok32) atomicAdd(&v32, 1);
        if (okbf) atomicAdd(&v16, 1);
        __syncthreads();
        if (threadIdx.x == 0) *dflag = (v16 > v32) ? 1 : 0;
    }
    int stride = gridDim.x * blockDim.x;
    int i0 = blockIdx.x * blockDim.x + threadIdx.x;
    for (u32 i = (u32)i0; i < HCAP; i += (u32)stride) {
        tab[i] = EMPTY64;
        tag[i] = 0;
    }
    for (int i = i0; i < MAXV; i += stride) cnt[i] = 0;
    if (i0 == 0) { *ocount = 0u; *total = 0; *fastflag = 0; }
}

__device__ __forceinline__ float load_ch(const void* pts, int i, int j, int bf) {
    if (bf) return bf2f(((const u16*)pts)[i * 5 + j]);
    return ((const float*)pts)[i * 5 + j];
}

// Exact f32 sub+div+floor, matching reference arithmetic. -1 if out of range.
__device__ __forceinline__ int point_key(const void* pts, int i, int bf) {
    float x = load_ch(pts, i, 0, bf);
    float y = load_ch(pts, i, 1, bf);
    float z = load_ch(pts, i, 2, bf);
    int cx = (int)floorf((x - (-75.2f)) / 0.1f);
    int cy = (int)floorf((y - (-75.2f)) / 0.1f);
    int cz = (int)floorf((z - (-2.0f)) / 0.15f);
    if (cx < 0 || cx >= GXC || cy < 0 || cy >= GYC || cz < 0 || cz >= GZC) return -1;
    return (cz * GYC + cy) * GXC + cx;
}

// Canonical kernel: fused prefix flags + packed u64 hash insert. CAS winner
// writes the tag (single writer per slot). Dups emit (slot,idx) records;
// their flag-clears are DEFERRED to k_clear (a dup's flag byte may belong to
// a block that hasn't flagged yet -> inline clear would race).
__global__ void Voxelization_87136296501765_kernel(
        const void* pts, int Peff, const int* dflag,
        u64* tab, u16* tag, u8* flags, u64* extras, u32* bcount,
        u64* ovf, u32* ocount) {
    __shared__ u32 s_cnt;
    if (threadIdx.x == 0) s_cnt = 0;
    __syncthreads();
    int i = blockIdx.x * 256 + threadIdx.x;
    bool has = false;
    u32 eslot = 0, eidx = 0;
    if (i < Peff) {
        int key = point_key(pts, i, *dflag);
        flags[i] = (u8)(key >= 0);
        if (key >= 0) {
            u64 mine = ((u64)(u32)key << 32) | (u32)i;
            u32 slot = hslot(key);
            for (;;) {                      // claims <= Peff <= HCAP/2: safe
                u64 prev = atomicCAS(&tab[slot], EMPTY64, mine);
                if (prev == EMPTY64) {      // first writer claims slot
                    tag[slot] = htag(key);
                    break;
                }
                if ((u32)(prev >> 32) == (u32)key) {  // same voxel -> dup
                    u32 pm = (u32)prev;
                    if (pm > (u32)i) {
                        u64 old = atomicMin(&tab[slot], mine);
                        u32 om = (u32)old;
                        eidx = (om > (u32)i) ? om : (u32)i;
                    } else {
                        eidx = (u32)i;
                    }
                    eslot = slot;
                    has = true;
                    break;
                }
                slot = (slot + 1u) & HMASK;
            }
        }
    }
    if (has) {
        u32 pos = atomicAdd(&s_cnt, 1u);
        u64 rec = ((u64)eslot << 32) | eidx;
        if (pos < SEGC) {
            extras[(size_t)blockIdx.x * SEGC + pos] = rec;
        } else {
            u32 op = atomicAdd(ocount, 1u);
            if (op < OCAP) ovf[op] = rec;
        }
    }
    __syncthreads();
    if (threadIdx.x == 0) bcount[blockIdx.x] = s_cnt;
}

// Clear dup flags (~1K random bytes on bench input).
__global__ void k_clear(const u64* extras, const u32* bcount, const u64* ovf,
                        const u32* ocount, int nbp, u8* flags) {
    int b = blockIdx.x;
    u64 rec;
    if (b < nbp) {
        u32 c = bcount[b];
        if (c > SEGC) c = SEGC;
        if (threadIdx.x >= c) return;
        rec = extras[(size_t)b * SEGC + threadIdx.x];
    } else {
        u32 j = (u32)(b - nbp) * 256 + threadIdx.x;
        u32 oc = *ocount;
        if (oc > OCAP) oc = OCAP;
        if (j >= oc) return;
        rec = ovf[j];
    }
    flags[(u32)rec] = 0;
}

// flags -> per-block exclusive rank + block sums.
__global__ void k_scan1(const u8* flags, u8* prefix, int* bsums, int n) {
    __shared__ int sh[256];
    int t = threadIdx.x;
    int i = blockIdx.x * 256 + t;
    int v = (i < n) ? (int)flags[i] : 0;
    sh[t] = v;
    __syncthreads();
    for (int off = 1; off < 256; off <<= 1) {
        int xv = (t >= off) ? sh[t - off] : 0;
        __syncthreads();
        sh[t] += xv;
        __syncthreads();
    }
    if (i < n) prefix[i] = (u8)(sh[t] - v);
    if (t == 255) bsums[blockIdx.x] = sh[255];
}

// Single-block scan of nbp (<=1024) block sums. Writes total, fastflag, vnum.
__global__ void k_scan2p(const int* bsums, int nbp, int* bpre,
                         int* total, int* fastflag, float* out) {
    __shared__ int sh[256];
    int t = threadIdx.x;
    int C = (nbp + 255) / 256;
    int lo = t * C;
    int hi = lo + C < nbp ? lo + C : nbp;
    int s = 0;
    for (int i = lo; i < hi; i++) s += bsums[i];
    sh[t] = s;
    __syncthreads();
    for (int off = 1; off < 256; off <<= 1) {
        int xv = (t >= off) ? sh[t - off] : 0;
        __syncthreads();
        sh[t] += xv;
        __syncthreads();
    }
    int run = sh[t] - s;
    for (int i = lo; i < hi; i++) { bpre[i] = run; run += bsums[i]; }
    if (t == 255) {
        int T = sh[255];
        *total = T;
        *fastflag = (T >= MAXV) ? 1 : 0;
        if (T > MAXV) T = MAXV;
        out[OUT_VNUM] = bfround((float)T);
    }
}

// Fused assign + suffix lookup.
// Blocks [0,nbp): prefix assign (firsts) + extras tail.
// Blocks [nbp,nbp+nbs2): suffix, 2 points/thread (512/block): tag-filtered
//   probes; tab read only on tag match. ~0.65% hit rate.
// Blocks beyond: overflow records.
__global__ void k_assign_lookup(const void* pts, int N, int Peff,
                                const int* dflag, const int* fastflag,
                                const u8* flags, const u8* prefix,
                                const int* bpre, const u64* tab,
                                const u16* tag,
                                const u64* extras, const u32* bcount,
                                const u64* ovf, const u32* ocount,
                                int nbp, int nbs2,
                                u64* firsts, int* cnt, int* lists) {
    int b = blockIdx.x;
    int t = threadIdx.x;
    u64 rec;
    if (b < nbp) {
        int i = b * 256 + t;
        int vbase = bpre[b];
        if (vbase < MAXV && i < Peff && flags[i]) {
            int v = (int)prefix[i] + vbase;
            if (v < MAXV) {
                int key = point_key(pts, i, *dflag);  // valid by construction
                firsts[v] = ((u64)(u32)key << 32) | (u32)i;
            }
        }
        u32 c = bcount[b];
        if (c > SEGC) c = SEGC;
        if ((u32)t >= c) return;
        rec = extras[(size_t)b * SEGC + t];
    } else if (b < nbp + nbs2) {
        if (*fastflag == 0) return;
        int bf = *dflag;
        int i1 = Peff + (b - nbp) * 512 + t;
        int i2 = i1 + 256;
        int k1 = (i1 < N) ? point_key(pts, i1, bf) : -1;
        int k2 = (i2 < N) ? point_key(pts, i2, bf) : -1;
#pragma unroll
        for (int s = 0; s < 2; s++) {
            int key = s ? k2 : k1;
            int i = s ? i2 : i1;
            if (key < 0) continue;
            u16 tg = htag(key);
            u32 slot = hslot(key);
            for (;;) {
                u16 g = tag[slot];
                if (g == 0) break;          // empty slot -> voxel not opened
                if (g == tg) {
                    u64 e = tab[slot];
                    if ((u32)(e >> 32) == (u32)key) {
                        u32 f = (u32)e;
                        int v = (int)prefix[f] + bpre[f >> 8];
                        if (v < MAXV) {
                            int pos = atomicAdd(&cnt[v], 1);
                            if (pos < LCAP) lists[v * LCAP + pos] = i;
                        }
                        break;
                    }                        // false positive -> keep probing
                }
                slot = (slot + 1u) & HMASK;
            }
        }
        return;
    } else {
        u32 j = (u32)(b - nbp - nbs2) * 256 + t;
        u32 oc = *ocount;
        if (oc > OCAP) oc = OCAP;
        if (j >= oc) return;
        rec = ovf[j];
    }
    u32 slot = (u32)(rec >> 32);
    u32 pidx = (u32)rec;
    u32 f = (u32)tab[slot];                 // LE low word = min idx
    int v = (int)prefix[f] + bpre[f >> 8];
    if (v >= MAXV) return;
    int pos = atomicAdd(&cnt[v], 1);
    if (pos < LCAP) lists[v * LCAP + pos] = (int)pidx;
}

// ---- Fallback path (distinct(prefix) < MAXV; gated, never on bench) ----

__device__ __forceinline__ u32 fhslot(int key, u32 fhmask) {
    return (((u32)key * 2654435761u) >> 9) & fhmask;
}

// ftab=EMPTY, cnt=0, ocount=0, and validity flags for ALL N (so finsert's
// inline dup-clear is single-writer-per-byte).
__global__ void k_finit(const int* fastflag, const void* pts, int N,
                        const int* dflag, u64* ftab, u32 fhcap, int* cnt,
                        u32* ocount, u8* flags) {
    if (*fastflag) return;
    int stride = gridDim.x * blockDim.x;
    int i0 = blockIdx.x * blockDim.x + threadIdx.x;
    for (u32 i = (u32)i0; i < fhcap; i += (u32)stride) ftab[i] = EMPTY64;
    for (int i = i0; i < MAXV; i += stride) cnt[i] = 0;
    int bf = *dflag;
    for (int i = i0; i < N; i += stride)
        flags[i] = (u8)(point_key(pts, i, bf) >= 0);
    if (i0 == 0) *ocount = 0u;
}

__global__ void k_finsert(const int* fastflag, const void* pts, int N,
                          const int* dflag, u64* ftab, u32 fhmask, u8* flags,
                          u64* extras, u32* bcount, u64* ovf, u32* ocount) {
    if (*fastflag) return;
    __shared__ u32 s_cnt;
    if (threadIdx.x == 0) s_cnt = 0;
    __syncthreads();
    int i = blockIdx.x * 256 + threadIdx.x;
    bool has = false;
    u32 eslot = 0, eidx = 0;
    if (i < N) {
        int key = point_key(pts, i, *dflag);
        if (key >= 0) {
            u64 mine = ((u64)(u32)key << 32) | (u32)i;
            u32 slot = fhslot(key, fhmask);
            for (u32 tries = 0; tries <= fhmask; ++tries) {  // bounded
                u64 prev = atomicCAS(&ftab[slot], EMPTY64, mine);
                if (prev == EMPTY64) break;
                if ((u32)(prev >> 32) == (u32)key) {
                    u32 pm = (u32)prev;
                    if (pm > (u32)i) {
                        u64 old = atomicMin(&ftab[slot], mine);
                        u32 om = (u32)old;
                        eidx = (om > (u32)i) ? om : (u32)i;
                    } else {
                        eidx = (u32)i;
                    }
                    eslot = slot;
                    has = true;
                    flags[eidx] = 0;
                    break;
                }
                slot = (slot + 1u) & fhmask;
            }
        }
    }
    if (has) {
        u32 pos = atomicAdd(&s_cnt, 1u);
        u64 rec = ((u64)eslot << 32) | eidx;
        if (pos < SEGC) {
            extras[(size_t)blockIdx.x * SEGC + pos] = rec;
        } else {
            u32 op = atomicAdd(ocount, 1u);
            if (op < OCAP) ovf[op] = rec;
        }
    }
    __syncthreads();
    if (threadIdx.x == 0) bcount[blockIdx.x] = s_cnt;
}

__global__ void k_fscan1(const int* fastflag, const u8* flags, u8* prefix,
                         int* bsums, int n) {
    if (*fastflag) return;
    __shared__ int sh[256];
    int t = threadIdx.x;
    int i = blockIdx.x * 256 + t;
    int v = (i < n) ? (int)flags[i] : 0;
    sh[t] = v;
    __syncthreads();
    for (int off = 1; off < 256; off <<= 1) {
        int xv = (t >= off) ? sh[t - off] : 0;
        __syncthreads();
        sh[t] += xv;
        __syncthreads();
    }
    if (i < n) prefix[i] = (u8)(sh[t] - v);
    if (t == 255) bsums[blockIdx.x] = sh[255];
}

__global__ void k_fscan2(const int* fastflag, const int* bsums, int nb,
                         int* bpre, int* total, float* out) {
    if (*fastflag) return;
    __shared__ int sh[256];
    int t = threadIdx.x;
    int C = (nb + 255) / 256;
    int lo = t * C;
    int hi = lo + C < nb ? lo + C : nb;
    int s = 0;
    for (int i = lo; i < hi; i++) s += bsums[i];
    sh[t] = s;
    __syncthreads();
    for (int off = 1; off < 256; off <<= 1) {
        int xv = (t >= off) ? sh[t - off] : 0;
        __syncthreads();
        sh[t] += xv;
        __syncthreads();
    }
    int run = sh[t] - s;
    for (int i = lo; i < hi; i++) { bpre[i] = run; run += bsums[i]; }
    if (t == 255) {
        int T = sh[255];
        *total = T;
        if (T > MAXV) T = MAXV;
        out[OUT_VNUM] = bfround((float)T);
    }
}

__global__ void k_fassign(const int* fastflag, const void* pts, int N,
                          const int* dflag, const u8* flags, const u8* prefix,
                          const int* bpre, const u64* ftab, const u64* extras,
                          const u32* bcount, const u64* ovf, const u32* ocount,
                          int nb, u64* firsts, int* cnt, int* lists) {
    if (*fastflag) return;
    int b = blockIdx.x;
    int t = threadIdx.x;
    u64 rec;
    if (b < nb) {
        int i = b * 256 + t;
        int vbase = bpre[b];
        if (vbase < MAXV && i < N && flags[i]) {
            int v = (int)prefix[i] + vbase;
            if (v < MAXV) {
                int key = point_key(pts, i, *dflag);
                firsts[v] = ((u64)(u32)key << 32) | (u32)i;
            }
        }
        u32 c = bcount[b];
        if (c > SEGC) c = SEGC;
        if ((u32)t >= c) return;
        rec = extras[(size_t)b * SEGC + t];
    } else {
        u32 j = (u32)(b - nb) * 256 + t;
        u32 oc = *ocount;
        if (oc > OCAP) oc = OCAP;
        if (j >= oc) return;
        rec = ovf[j];
    }
    u32 slot = (u32)(rec >> 32);
    u32 pidx = (u32)rec;
    u32 f = (u32)ftab[slot];
    int v = (int)prefix[f] + bpre[f >> 8];
    if (v >= MAXV) return;
    int pos = atomicAdd(&cnt[v], 1);
    if (pos < LCAP) lists[v * LCAP + pos] = (int)pidx;
}

// Sole output writer (d_out is poisoned each call): per v writes the full
// 10x5 voxel block, coors (coalesced in v), npv.
__global__ void k_write(const void* pts, const int* dflag, const u64* firsts,
                        const int* cnt, const int* lists, const int* total,
                        float* out) {
    int v = blockIdx.x * blockDim.x + threadIdx.x;
    if (v >= MAXV) return;
    int T = *total;
    if (T > MAXV) T = MAXV;
    float* dst = out + (size_t)v * MAXP * 5;
    if (v >= T) {
        for (int j = 0; j < MAXP * 5; j++) dst[j] = 0.0f;
        out[OUT_COORS + v * 3 + 0] = -1.0f;
        out[OUT_COORS + v * 3 + 1] = -1.0f;
        out[OUT_COORS + v * 3 + 2] = -1.0f;
        out[OUT_NPV + v] = 0.0f;
        return;
    }
    u64 fe = firsts[v];
    u32 key = (u32)(fe >> 32);
    int f = (int)(u32)fe;
    int cx = (int)(key % GXC);
    u32 r = key / GXC;
    int cy = (int)(r % GYC);
    int cz = (int)(r / GYC);
    out[OUT_COORS + v * 3 + 0] = bfround((float)cz);
    out[OUT_COORS + v * 3 + 1] = bfround((float)cy);
    out[OUT_COORS + v * 3 + 2] = bfround((float)cx);
    int c = cnt[v];
    int np = 1 + c;
    if (np > MAXP) np = MAXP;
    out[OUT_NPV + v] = (float)np;
    int bf = *dflag;
    for (int j = 0; j < 5; j++) dst[j] = bfround(load_ch(pts, f, j, bf));
    if (c > 0) {
        int m = (c < LCAP) ? c : LCAP;
        int idx[LCAP];
        for (int j = 0; j < m; j++) idx[j] = lists[v * LCAP + j];
        for (int a = 1; a < m; a++) {  // sort dup indices -> insertion order
            int kk = idx[a];
            int b2 = a - 1;
            while (b2 >= 0 && idx[b2] > kk) { idx[b2 + 1] = idx[b2]; b2--; }
            idx[b2 + 1] = kk;
        }
        for (int rr = 1; rr < np; rr++) {
            int p = idx[rr - 1];
            for (int j = 0; j < 5; j++)
                dst[rr * 5 + j] = bfround(load_ch(pts, p, j, bf));
        }
    }
    for (int rr = np; rr < MAXP; rr++)
        for (int j = 0; j < 5; j++) dst[rr * 5 + j] = 0.0f;
}

extern "C" void kernel_launch(void* const* d_in, const int* in_sizes, int n_in,
                              void* d_out, int out_size, void* d_ws, size_t ws_size,
                              hipStream_t stream) {
    (void)n_in; (void)out_size;
    const void* pts = d_in[0];
    int N = in_sizes[0] / 5;
    float* out = (float*)d_out;
    if (N <= 0 || N > 16384 * 256) return;

    int Peff = N < PPREF ? N : PPREF;
    int nbp = (Peff + 255) / 256;
    int nbs2 = (N > Peff) ? (N - Peff + 511) / 512 : 0;
    int nb = (N + 255) / 256;
    size_t npad = ((size_t)N + 255) & ~(size_t)255;

    // ws: flags[npad] | prefix[npad] | bsums/bpre[16384]*4 | scalars |
    //     tab[HCAP]*8 | tag[HCAP]*2 | firsts[MAXV]*8 | cnt[MAXV]*4 |
    //     lists[MAXV*LCAP]*4 | extras[nb*SEGC]*8 | bcount[nb]*4 |
    //     ovf[OCAP]*8 | ftab[fhcap]*8   (~36.2 MB at N=2M, fhcap=2^21)
    size_t base_need = npad + npad + 16384 * 8 + 512
                + (size_t)HCAP * 8 + (size_t)HCAP * 2
                + (size_t)MAXV * 8 + (size_t)MAXV * 4 + (size_t)MAXV * LCAP * 4
                + (size_t)nb * SEGC * 8 + (((size_t)nb * 4 + 255) & ~(size_t)255)
                + (size_t)OCAP * 8;
    u32 fhcap = 1u << 22;                        // prefer 32MB fallback table
    if (ws_size < base_need + ((size_t)8 << 22)) fhcap = 1u << 21;
    if (ws_size < base_need + ((size_t)8 << 21)) return;
    u32 fhmask = fhcap - 1u;

    char* w = (char*)d_ws;
    u8*  flags  = (u8*)w;   w += npad;
    u8*  prefix = (u8*)w;   w += npad;
    int* bsums  = (int*)w;  w += 16384 * 4;
    int* bpre   = (int*)w;  w += 16384 * 4;
    int* total  = (int*)w;  w += 128;
    int* dflag  = (int*)w;  w += 128;
    u32* ocount = (u32*)w;  w += 128;
    int* fastflag = (int*)w; w += 128;
    u64* tab    = (u64*)w;  w += (size_t)HCAP * 8;
    u16* tag    = (u16*)w;  w += (size_t)HCAP * 2;
    u64* firsts = (u64*)w;  w += (size_t)MAXV * 8;
    int* cnt    = (int*)w;  w += (size_t)MAXV * 4;
    int* lists  = (int*)w;  w += (size_t)MAXV * LCAP * 4;
    u64* extras = (u64*)w;  w += (size_t)nb * SEGC * 8;
    u32* bcount = (u32*)w;  w += ((size_t)nb * 4 + 255) & ~(size_t)255;
    u64* ovf    = (u64*)w;  w += (size_t)OCAP * 8;
    u64* ftab   = (u64*)w;

    k_init<<<2048, 256, 0, stream>>>(tab, tag, cnt, N, (const u16*)pts,
                                     dflag, ocount, total, fastflag);
    Voxelization_87136296501765_kernel<<<nbp, 256, 0, stream>>>(
        pts, Peff, dflag, tab, tag, flags, extras, bcount, ovf, ocount);
    k_clear<<<nbp + OCAP / 256, 256, 0, stream>>>(extras, bcount, ovf,
                                                  ocount, nbp, flags);
    k_scan1<<<nbp, 256, 0, stream>>>(flags, prefix, bsums, Peff);
    k_scan2p<<<1, 256, 0, stream>>>(bsums, nbp, bpre, total, fastflag, out);
    k_assign_lookup<<<nbp + nbs2 + OCAP / 256, 256, 0, stream>>>(
        pts, N, Peff, dflag, fastflag, flags, prefix, bpre, tab, tag,
        extras, bcount, ovf, ocount, nbp, nbs2, firsts, cnt, lists);
    if (N > Peff) {
        // gated fallback (runs only if distinct(prefix) < MAXV)
        k_finit<<<2048, 256, 0, stream>>>(fastflag, pts, N, dflag, ftab,
                                          fhcap, cnt, ocount, flags);
        k_finsert<<<nb, 256, 0, stream>>>(fastflag, pts, N, dflag, ftab,
                                          fhmask, flags, extras, bcount,
                                          ovf, ocount);
        k_fscan1<<<nb, 256, 0, stream>>>(fastflag, flags, prefix, bsums, N);
        k_fscan2<<<1, 256, 0, stream>>>(fastflag, bsums, nb, bpre, total, out);
        k_fassign<<<nb + OCAP / 256, 256, 0, stream>>>(
            fastflag, pts, N, dflag, flags, prefix, bpre, ftab, extras,
            bcount, ovf, ocount, nb, firsts, cnt, lists);
    }
    k_write<<<(MAXV + 255) / 256, 256, 0, stream>>>(pts, dflag, firsts, cnt,
                                                    lists, total, out);
}